// Round 5
// baseline (1204.573 us; speedup 1.0000x reference)
//
#include <hip/hip_runtime.h>
#include <hip/hip_bf16.h>
#include <math.h>

#define MM 256
#define LL 4096
#define TT 2048

typedef __attribute__((ext_vector_type(8))) short bf16x8;
typedef __attribute__((ext_vector_type(4))) float f32x4;
typedef unsigned short ushort_t;

// workspace float offsets
#define OFF_G      131072
#define OFF_Q      262144
#define OFF_D      266240
#define OFF_V      270336
#define OFF_U      274432
#define OFF_UP     278528
#define OFF_BAR    286720   // 64 floats of barrier state
#define ZERO_FL    290816   // zero range [0, ZERO_FL)
#define OFF_RINVP  290816
#define OFF_GP     421888
#define OFF_APL    552960
#define OFF_XPL    2650112
#define OFF_ATP    3698688
#define OFF_WTP    5795840
#define OFF_W      7892992
#define OFF_XA     9990144
#define OFF_XB     10121216
#define OFF_TT     10252288

#define MFMA3(ACC, AH, AL, BH, BL)                                              \
  ACC = __builtin_amdgcn_mfma_f32_16x16x32_bf16(AH, BH, ACC, 0, 0, 0);          \
  ACC = __builtin_amdgcn_mfma_f32_16x16x32_bf16(AH, BL, ACC, 0, 0, 0);          \
  ACC = __builtin_amdgcn_mfma_f32_16x16x32_bf16(AL, BH, ACC, 0, 0, 0);

__device__ __forceinline__ void split_bf16(float x, ushort_t& h, ushort_t& l) {
  __hip_bfloat16 bh = __float2bfloat16(x);
  h = *(ushort_t*)&bh;
  __hip_bfloat16 bl = __float2bfloat16(x - __bfloat162float(bh));
  l = *(ushort_t*)&bl;
}

// ---- software grid barrier (all blocks co-resident; device-scope) ----
__device__ __forceinline__ void gbar(unsigned* cnt, unsigned* gen, unsigned nblk) {
  __threadfence();
  __syncthreads();
  if (threadIdx.x == 0) {
    unsigned g = __hip_atomic_load(gen, __ATOMIC_RELAXED, __HIP_MEMORY_SCOPE_AGENT);
    unsigned a = __hip_atomic_fetch_add(cnt, 1u, __ATOMIC_ACQ_REL, __HIP_MEMORY_SCOPE_AGENT);
    if (a == nblk - 1) {
      __hip_atomic_store(cnt, 0u, __ATOMIC_RELAXED, __HIP_MEMORY_SCOPE_AGENT);
      __hip_atomic_store(gen, g + 1u, __ATOMIC_RELEASE, __HIP_MEMORY_SCOPE_AGENT);
    } else {
      while (__hip_atomic_load(gen, __ATOMIC_ACQUIRE, __HIP_MEMORY_SCOPE_AGENT) == g) {
        __builtin_amdgcn_s_sleep(1);
      }
    }
  }
  __syncthreads();
  __threadfence();
}

// ---------------- reductions ----------------
__device__ __forceinline__ float wave_red_sum(float v) {
#pragma unroll
  for (int o = 32; o > 0; o >>= 1) v += __shfl_down(v, o);
  return v;
}
__device__ __forceinline__ float wave_red_max(float v) {
#pragma unroll
  for (int o = 32; o > 0; o >>= 1) v = fmaxf(v, __shfl_down(v, o));
  return v;
}
__device__ float blk_red_sum(float v) {
  __shared__ float sh[4];
  int lane = threadIdx.x & 63, wv = threadIdx.x >> 6;
  v = wave_red_sum(v);
  __syncthreads();
  if (lane == 0) sh[wv] = v;
  __syncthreads();
  return sh[0] + sh[1] + sh[2] + sh[3];
}
__device__ float blk_red_max(float v) {
  __shared__ float shm[4];
  int lane = threadIdx.x & 63, wv = threadIdx.x >> 6;
  v = wave_red_max(v);
  __syncthreads();
  if (lane == 0) shm[wv] = v;
  __syncthreads();
  return fmaxf(fmaxf(shm[0], shm[1]), fmaxf(shm[2], shm[3]));
}

// ---------------- prep: zero state + convert A and X to split-bf16 planes ----------------
__global__ __launch_bounds__(256) void k_prep(float* __restrict__ ws,
                                              const float* __restrict__ Are,
                                              const float* __restrict__ Aim,
                                              const float* __restrict__ Xre,
                                              const float* __restrict__ Xim,
                                              const float* __restrict__ gamma) {
  int bid = blockIdx.x, tid = threadIdx.x;
  if (bid < ZERO_FL / 256) {                       // zero R,G,q,d,v,u,up,bar
    int idx = bid * 256 + tid;
    float v = 0.0f;
    if (idx < 131072 && (idx % 514) == 0) v = 0.01f;  // ridge on R diag (.x)
    ws[idx] = v;
  } else if (bid < ZERO_FL / 256 + (MM * LL) / 256) {  // A -> planes, sqrt(gamma) folded
    int idx = (bid - ZERO_FL / 256) * 256 + tid;
    ushort_t* dst = (ushort_t*)(ws + OFF_APL);
    float s = sqrtf(gamma[idx & (LL - 1)]);
    ushort_t h, l;
    split_bf16(Are[idx] * s, h, l);
    dst[idx] = h;
    dst[idx + MM * LL] = l;
    split_bf16(Aim[idx] * s, h, l);
    dst[idx + 2 * MM * LL] = h;
    dst[idx + 3 * MM * LL] = l;
  } else {                                          // X -> planes
    int idx = (bid - ZERO_FL / 256 - (MM * LL) / 256) * 256 + tid;
    ushort_t* dst = (ushort_t*)(ws + OFF_XPL);
    ushort_t h, l;
    split_bf16(Xre[idx], h, l);
    dst[idx] = h;
    dst[idx + MM * TT] = l;
    split_bf16(Xim[idx], h, l);
    dst[idx + 2 * MM * TT] = h;
    dst[idx + 3 * MM * TT] = l;
  }
}

// ---------------- MFMA gram tile (device fn) ----------------
__device__ void gram_tile(const ushort_t* __restrict__ pl, size_t PS, int K,
                          int kbeg, int kend, int tile, float* __restrict__ C) {
  const ushort_t* prh = pl;
  const ushort_t* prl = pl + PS;
  const ushort_t* pih = pl + 2 * PS;
  const ushort_t* pil = pl + 3 * PS;
  int i0 = (tile >> 2) * 64, j0 = (tile & 3) * 64;
  int lane = threadIdx.x & 63, wv = threadIdx.x >> 6;
  int m = i0 + wv * 16 + (lane & 15);
  int kq = (lane >> 4) * 8;
  f32x4 z = {0.f, 0.f, 0.f, 0.f};
  f32x4 Zrr[4], Zri[4], Zir[4], Zii[4];
#pragma unroll
  for (int s = 0; s < 4; ++s) { Zrr[s] = z; Zri[s] = z; Zir[s] = z; Zii[s] = z; }
  for (int k0 = kbeg; k0 < kend; k0 += 32) {
    size_t ao = (size_t)m * K + k0 + kq;
    bf16x8 arh = *(const bf16x8*)(prh + ao);
    bf16x8 arl = *(const bf16x8*)(prl + ao);
    bf16x8 aih = *(const bf16x8*)(pih + ao);
    bf16x8 ail = *(const bf16x8*)(pil + ao);
#pragma unroll
    for (int s = 0; s < 4; ++s) {
      size_t bo = (size_t)(j0 + s * 16 + (lane & 15)) * K + k0 + kq;
      bf16x8 brh = *(const bf16x8*)(prh + bo);
      bf16x8 brl = *(const bf16x8*)(prl + bo);
      bf16x8 bih = *(const bf16x8*)(pih + bo);
      bf16x8 bil = *(const bf16x8*)(pil + bo);
      MFMA3(Zrr[s], arh, arl, brh, brl);
      MFMA3(Zri[s], arh, arl, bih, bil);
      MFMA3(Zir[s], aih, ail, brh, brl);
      MFMA3(Zii[s], aih, ail, bih, bil);
    }
  }
  int rbase = i0 + wv * 16 + (lane >> 4) * 4;
#pragma unroll
  for (int s = 0; s < 4; ++s) {
    int col = j0 + s * 16 + (lane & 15);
#pragma unroll
    for (int r = 0; r < 4; ++r) {
      float re = Zrr[s][r] + Zii[s][r];   // a * conj(b)
      float im = Zir[s][r] - Zri[s][r];
      float* p = C + ((size_t)(rbase + r) * 256 + col) * 2;
      atomicAdd(p, re);
      atomicAdd(p + 1, im);
    }
  }
}

// ---------------- both grams in one launch (independent halves) ----------------
__global__ __launch_bounds__(256) void k_gram_both(float* __restrict__ ws) {
  int bid = blockIdx.x;
  if (bid < 256) {  // A-gram: 16 tiles x 16 K-splits, K=4096
    const ushort_t* pl = (const ushort_t*)(ws + OFF_APL);
    int tile = bid & 15, ks = bid >> 4;
    gram_tile(pl, (size_t)MM * LL, LL, ks * 256, ks * 256 + 256, tile, ws);
  } else {          // X-gram: 16 tiles x 8 K-splits, K=2048
    int b2 = bid - 256;
    const ushort_t* pl = (const ushort_t*)(ws + OFF_XPL);
    int tile = b2 & 15, ks = b2 >> 4;
    gram_tile(pl, (size_t)MM * TT, TT, ks * 256, ks * 256 + 256, tile, ws + OFF_G);
  }
}

// ---------------- mid: G -> bf16 planes  +  A^T -> bf16 planes ----------------
__global__ __launch_bounds__(256) void k_mid(float* __restrict__ ws,
                                             const float* __restrict__ Are,
                                             const float* __restrict__ Aim) {
  __shared__ float tr[32][33], ti[32][33];
  int bid = blockIdx.x, tid = threadIdx.x;
  if (bid < 256) {  // conv256: G -> Gp
    const float2* src = (const float2*)(ws + OFF_G);
    ushort_t* dst = (ushort_t*)(ws + OFF_GP);
    int idx = bid * 256 + tid;
    float2 v = src[idx];
    ushort_t h, l;
    split_bf16(v.x, h, l);
    dst[idx] = h;
    dst[idx + 65536] = l;
    split_bf16(v.y, h, l);
    dst[idx + 131072] = h;
    dst[idx + 196608] = l;
  } else {          // transpA: [256][4096] -> planes [4096][256]
    int b2 = bid - 256;
    ushort_t* dst = (ushort_t*)(ws + OFF_ATP);
    int c0 = (b2 & 127) * 32, r0 = (b2 >> 7) * 32;
    int tx = tid & 31, tg = tid >> 5;
#pragma unroll
    for (int i = 0; i < 4; ++i) {
      int r = tg + 8 * i;
      tr[r][tx] = Are[(size_t)(r0 + r) * LL + c0 + tx];
      ti[r][tx] = Aim[(size_t)(r0 + r) * LL + c0 + tx];
    }
    __syncthreads();
#pragma unroll
    for (int i = 0; i < 4; ++i) {
      int rr = tg + 8 * i;
      size_t o = (size_t)(c0 + rr) * 256 + r0 + tx;
      ushort_t h, l;
      split_bf16(tr[tx][rr], h, l);
      dst[o] = h;
      dst[o + 1048576] = l;
      split_bf16(ti[tx][rr], h, l);
      dst[o + 2097152] = h;
      dst[o + 3145728] = l;
    }
  }
}

// ---------------- persistent Newton-Schulz: X0 + 6 iters + conv to planes ----------------
__global__ __launch_bounds__(256) void k_newton(float* __restrict__ ws) {
  __shared__ float2 As[16][64];
  __shared__ float2 Bs[64][16];
  unsigned* cnt = (unsigned*)(ws + OFF_BAR);
  unsigned* gen = (unsigned*)(ws + OFF_BAR + 16);
  const float2* Rc = (const float2*)ws;
  float2* Xa = (float2*)(ws + OFF_XA);
  float2* Xb = (float2*)(ws + OFF_XB);
  float2* Tt = (float2*)(ws + OFF_TT);
  int bid = blockIdx.x, tid = threadIdx.x;
  int i0 = (bid >> 4) * 16, j0 = (bid & 15) * 16;
  int tx = tid & 15, ty = tid >> 4;
  int gi = i0 + ty, gj = j0 + tx;

  // X0 = diag(R)^-1
  float v0 = (gi == gj) ? (1.0f / Rc[gi * 257].x) : 0.0f;
  Xa[gi * 256 + gj] = make_float2(v0, 0.0f);
  gbar(cnt, gen, 256);

  float2* cur = Xa;
  float2* oth = Xb;
  for (int it = 0; it < 6; ++it) {
    // phase 1: T = R @ cur
    {
      float accx = 0.f, accy = 0.f;
      for (int k0 = 0; k0 < 256; k0 += 64) {
        __syncthreads();
        for (int e = tid; e < 1024; e += 256) {
          int r = e >> 6, c = e & 63;
          As[r][c] = Rc[(i0 + r) * 256 + k0 + c];
        }
        for (int e = tid; e < 1024; e += 256) {
          int k = e >> 4, j = e & 15;
          Bs[k][j] = cur[(k0 + k) * 256 + j0 + j];
        }
        __syncthreads();
#pragma unroll 16
        for (int kk = 0; kk < 64; ++kk) {
          float2 a = As[ty][kk], b = Bs[kk][tx];
          accx += a.x * b.x - a.y * b.y;
          accy += a.x * b.y + a.y * b.x;
        }
      }
      Tt[gi * 256 + gj] = make_float2(accx, accy);
    }
    gbar(cnt, gen, 256);
    // phase 2: X' = 2*cur - cur @ T
    {
      float accx = 0.f, accy = 0.f;
      for (int k0 = 0; k0 < 256; k0 += 64) {
        __syncthreads();
        for (int e = tid; e < 1024; e += 256) {
          int r = e >> 6, c = e & 63;
          As[r][c] = cur[(i0 + r) * 256 + k0 + c];
        }
        for (int e = tid; e < 1024; e += 256) {
          int k = e >> 4, j = e & 15;
          Bs[k][j] = Tt[(k0 + k) * 256 + j0 + j];
        }
        __syncthreads();
#pragma unroll 16
        for (int kk = 0; kk < 64; ++kk) {
          float2 a = As[ty][kk], b = Bs[kk][tx];
          accx += a.x * b.x - a.y * b.y;
          accy += a.x * b.y + a.y * b.x;
        }
      }
      float2 x = cur[gi * 256 + gj];
      oth[gi * 256 + gj] = make_float2(2.0f * x.x - accx, 2.0f * x.y - accy);
    }
    gbar(cnt, gen, 256);
    float2* t = cur; cur = oth; oth = t;
  }
  // Rinv -> split-bf16 planes
  ushort_t* dst = (ushort_t*)(ws + OFF_RINVP);
  float2 vv = cur[gi * 256 + gj];
  int idx = gi * 256 + gj;
  ushort_t h, l;
  split_bf16(vv.x, h, l);
  dst[idx] = h;
  dst[idx + 65536] = l;
  split_bf16(vv.y, h, l);
  dst[idx + 131072] = h;
  dst[idx + 196608] = l;
}

// ---------------- wide MFMA tile (device fn) ----------------
// mode 0: Cout=W tile write + d[l] atomics (Aux = A planes fp32)
// mode 1: q[l] atomics (Wf = W fp32)
__device__ void wide_phase(const ushort_t* __restrict__ Ap, const ushort_t* __restrict__ Bp,
                           const float* __restrict__ AuxRe, const float* __restrict__ AuxIm,
                           const float2* __restrict__ Wf, float2* __restrict__ Cout,
                           float* __restrict__ dq, int mode, int i0, int j0) {
  const ushort_t* arh_p = Ap;
  const ushort_t* arl_p = Ap + 65536;
  const ushort_t* aih_p = Ap + 131072;
  const ushort_t* ail_p = Ap + 196608;
  const ushort_t* brh_p = Bp;
  const ushort_t* brl_p = Bp + 1048576;
  const ushort_t* bih_p = Bp + 2097152;
  const ushort_t* bil_p = Bp + 3145728;
  int lane = threadIdx.x & 63, wv = threadIdx.x >> 6;
  int m = i0 + wv * 16 + (lane & 15);
  int kq = (lane >> 4) * 8;
  f32x4 z = {0.f, 0.f, 0.f, 0.f};
  f32x4 Zrr[4], Zri[4], Zir[4], Zii[4];
#pragma unroll
  for (int s = 0; s < 4; ++s) { Zrr[s] = z; Zri[s] = z; Zir[s] = z; Zii[s] = z; }
  for (int k0 = 0; k0 < 256; k0 += 32) {
    size_t ao = (size_t)m * 256 + k0 + kq;
    bf16x8 arh = *(const bf16x8*)(arh_p + ao);
    bf16x8 arl = *(const bf16x8*)(arl_p + ao);
    bf16x8 aih = *(const bf16x8*)(aih_p + ao);
    bf16x8 ail = *(const bf16x8*)(ail_p + ao);
#pragma unroll
    for (int s = 0; s < 4; ++s) {
      size_t bo = (size_t)(j0 + s * 16 + (lane & 15)) * 256 + k0 + kq;
      bf16x8 brh = *(const bf16x8*)(brh_p + bo);
      bf16x8 brl = *(const bf16x8*)(brl_p + bo);
      bf16x8 bih = *(const bf16x8*)(bih_p + bo);
      bf16x8 bil = *(const bf16x8*)(bil_p + bo);
      MFMA3(Zrr[s], arh, arl, brh, brl);
      MFMA3(Zri[s], arh, arl, bih, bil);
      MFMA3(Zir[s], aih, ail, brh, brl);
      MFMA3(Zii[s], aih, ail, bih, bil);
    }
  }
  int rbase = i0 + wv * 16 + (lane >> 4) * 4;
#pragma unroll
  for (int s = 0; s < 4; ++s) {
    int col = j0 + s * 16 + (lane & 15);
    float part = 0.f;
#pragma unroll
    for (int r = 0; r < 4; ++r) {
      float re = Zrr[s][r] - Zii[s][r];   // a * b
      float im = Zri[s][r] + Zir[s][r];
      size_t o = (size_t)(rbase + r) * LL + col;
      if (mode == 0) {
        Cout[o] = make_float2(re, im);
        part += re * AuxRe[o] - im * AuxIm[o];
      } else {
        float2 w = Wf[o];
        part += w.x * re + w.y * im;
      }
    }
    part += __shfl_down(part, 32);
    part += __shfl_down(part, 16);
    if ((lane >> 4) == 0) atomicAdd(dq + col, part);
  }
}

// ---------------- persistent wide chain: W+d -> transpose W -> q ----------------
__global__ __launch_bounds__(256) void k_wide_chain(float* __restrict__ ws,
                                                    const float* __restrict__ Are,
                                                    const float* __restrict__ Aim) {
  __shared__ float tr[32][33], ti[32][33];
  unsigned* cnt = (unsigned*)(ws + OFF_BAR + 32);
  unsigned* gen = (unsigned*)(ws + OFF_BAR + 48);
  int bid = blockIdx.x, tid = threadIdx.x;
  float2* W = (float2*)(ws + OFF_W);
  // phase A: W = Rinv @ A  (+ d)
  {
    int j0 = (bid & 63) * 64, i0 = (bid >> 6) * 64;
    wide_phase((const ushort_t*)(ws + OFF_RINVP), (const ushort_t*)(ws + OFF_ATP),
               Are, Aim, nullptr, W, ws + OFF_D, 0, i0, j0);
  }
  gbar(cnt, gen, 256);
  // phase B: W^T -> split-bf16 planes (4 tiles of 32x32 per block)
  {
    ushort_t* dst = (ushort_t*)(ws + OFF_WTP);
    int tx = tid & 31, tg = tid >> 5;
    for (int sub = 0; sub < 4; ++sub) {
      int tt = bid * 4 + sub;
      int c0 = (tt & 127) * 32, r0 = (tt >> 7) * 32;
      __syncthreads();
#pragma unroll
      for (int i = 0; i < 4; ++i) {
        int r = tg + 8 * i;
        float2 w = W[(size_t)(r0 + r) * LL + c0 + tx];
        tr[r][tx] = w.x;
        ti[r][tx] = w.y;
      }
      __syncthreads();
#pragma unroll
      for (int i = 0; i < 4; ++i) {
        int rr = tg + 8 * i;
        size_t o = (size_t)(c0 + rr) * 256 + r0 + tx;
        ushort_t h, l;
        split_bf16(tr[tx][rr], h, l);
        dst[o] = h;
        dst[o + 1048576] = l;
        split_bf16(ti[tx][rr], h, l);
        dst[o + 2097152] = h;
        dst[o + 3145728] = l;
      }
    }
  }
  gbar(cnt, gen, 256);
  // phase C: q = col-sums of Re(conj(W) .* (G @ W))
  {
    int j0 = (bid & 63) * 64, i0 = (bid >> 6) * 64;
    wide_phase((const ushort_t*)(ws + OFF_GP), (const ushort_t*)(ws + OFF_WTP),
               nullptr, nullptr, W, nullptr, ws + OFF_Q, 1, i0, j0);
  }
}

// ---------------- v,u + LayerNorm (single block) ----------------
__global__ __launch_bounds__(256) void k_uvln(float* __restrict__ ws,
                                              const float* __restrict__ gamma,
                                              const float* __restrict__ delta,
                                              const float* __restrict__ lnw,
                                              const float* __restrict__ lnb) {
  const float* q = ws + OFF_Q;
  const float* d = ws + OFF_D;
  float* vvec = ws + OFF_V;
  float* uvec = ws + OFF_U;
  float* up = ws + OFF_UP;
  int tid = threadIdx.x;
  float dlt = 1.0f / (1.0f + expf(-delta[0]));
  float s = 0.f;
  for (int i = tid; i < LL; i += 256) {
    float v = q[i] / (d[i] + 1e-12f);
    float p = gamma[i];
    float u = p + dlt * (v - p);
    vvec[i] = v;
    uvec[i] = u;
    s += u;
  }
  float mu = blk_red_sum(s) * (1.0f / LL);
  float s2 = 0.f;
  for (int i = tid; i < LL; i += 256) { float dd = uvec[i] - mu; s2 += dd * dd; }
  float var = blk_red_sum(s2) * (1.0f / LL);
  float inv = rsqrtf(var + 1e-5f);
  for (int i = tid; i < LL; i += 256) up[i] = (uvec[i] - mu) * inv * lnw[i] + lnb[i];
}

// ---------------- gate row + attention row + final combine ----------------
__global__ __launch_bounds__(256) void k_gateattn(const float* __restrict__ ws,
                                                  const float* __restrict__ Wg,
                                                  const float* __restrict__ gb,
                                                  const float* __restrict__ inw,
                                                  const float* __restrict__ inb,
                                                  const float* __restrict__ outw,
                                                  const float* __restrict__ outb,
                                                  const float* __restrict__ gamma,
                                                  const float* __restrict__ lmbda,
                                                  float* __restrict__ out) {
  const float* uvec = ws + OFF_U;
  const float* up = ws + OFF_UP;
  const float* vvec = ws + OFF_V;
  int i = blockIdx.x, tid = threadIdx.x;
  // gate: g_i = sigmoid(Wg[i,:] . u + gb[i])
  const float4* wr = (const float4*)(Wg + (size_t)i * LL);
  const float4* u4 = (const float4*)uvec;
  float s = 0.f;
  for (int j = tid; j < LL / 4; j += 256) {
    float4 w = wr[j], x = u4[j];
    s += w.x * x.x + w.y * x.y + w.z * x.z + w.w * x.w;
  }
  float tot = blk_red_sum(s);
  float g = 1.0f / (1.0f + expf(-(tot + gb[i])));
  // attention row i
  float qv = up[i] * inw[0] + inb[0];
  float w1 = inw[1], b1 = inb[1], w2 = inw[2], b2 = inb[2];
  const float4* up4 = (const float4*)up;
  float mx = -3.4e38f;
  for (int j = tid; j < LL / 4; j += 256) {
    float4 u = up4[j];
    mx = fmaxf(mx, fmaxf(fmaxf(qv * (u.x * w1 + b1), qv * (u.y * w1 + b1)),
                         fmaxf(qv * (u.z * w1 + b1), qv * (u.w * w1 + b1))));
  }
  mx = blk_red_max(mx);
  float den = 0.f, num = 0.f;
  for (int j = tid; j < LL / 4; j += 256) {
    float4 u = up4[j];
    float e0 = expf(qv * (u.x * w1 + b1) - mx);
    float e1 = expf(qv * (u.y * w1 + b1) - mx);
    float e2 = expf(qv * (u.z * w1 + b1) - mx);
    float e3 = expf(qv * (u.w * w1 + b1) - mx);
    den += e0 + e1 + e2 + e3;
    num += e0 * (u.x * w2 + b2) + e1 * (u.y * w2 + b2) + e2 * (u.z * w2 + b2) + e3 * (u.w * w2 + b2);
  }
  den = blk_red_sum(den);
  num = blk_red_sum(num);
  if (tid == 0) {
    float attn = (num / den) * outw[0] + outb[0];
    float r = g * vvec[i] + (1.0f - g) * gamma[i] + attn - lmbda[0];
    out[i] = fmaxf(r, 0.0f);
  }
}

extern "C" void kernel_launch(void* const* d_in, const int* in_sizes, int n_in,
                              void* d_out, int out_size, void* d_ws, size_t ws_size,
                              hipStream_t stream) {
  const float* gamma = (const float*)d_in[0];
  const float* Are   = (const float*)d_in[1];
  const float* Aim   = (const float*)d_in[2];
  const float* Xre   = (const float*)d_in[3];
  const float* Xim   = (const float*)d_in[4];
  const float* lnw   = (const float*)d_in[5];
  const float* lnb   = (const float*)d_in[6];
  const float* inw   = (const float*)d_in[7];
  const float* inb   = (const float*)d_in[8];
  const float* outw  = (const float*)d_in[9];
  const float* outb  = (const float*)d_in[10];
  const float* gateW = (const float*)d_in[11];
  const float* gateb = (const float*)d_in[12];
  const float* delta = (const float*)d_in[13];
  const float* lmbda = (const float*)d_in[14];
  float* out = (float*)d_out;
  float* ws = (float*)d_ws;

  int prep_blocks = ZERO_FL / 256 + (MM * LL) / 256 + (MM * TT) / 256;  // 1136+4096+2048
  k_prep<<<prep_blocks, 256, 0, stream>>>(ws, Are, Aim, Xre, Xim, gamma);
  k_gram_both<<<384, 256, 0, stream>>>(ws);
  k_mid<<<1280, 256, 0, stream>>>(ws, Are, Aim);
  k_newton<<<256, 256, 0, stream>>>(ws);
  k_wide_chain<<<256, 256, 0, stream>>>(ws, Are, Aim);
  k_uvln<<<1, 256, 0, stream>>>(ws, gamma, delta, lnw, lnb);
  k_gateattn<<<LL, 256, 0, stream>>>(ws, gateW, gateb, inw, inb, outw, outb, gamma, lmbda, out);
}

// Round 6
// 356.768 us; speedup vs baseline: 3.3763x; 3.3763x over previous
//
#include <hip/hip_runtime.h>
#include <hip/hip_bf16.h>
#include <math.h>

#define MM 256
#define LL 4096
#define TT 2048

typedef __attribute__((ext_vector_type(8))) short bf16x8;
typedef __attribute__((ext_vector_type(4))) float f32x4;
typedef unsigned short ushort_t;

// workspace float offsets
#define OFF_G      131072
#define OFF_Q      262144
#define OFF_D      266240
#define OFF_V      270336
#define OFF_U      274432
#define OFF_UP     278528
#define ZERO_FL    290816   // zero range [0, ZERO_FL)
#define OFF_RINVP  290816
#define OFF_GP     421888
#define OFF_APL    552960
#define OFF_XPL    2650112
#define OFF_ATP    3698688
#define OFF_WTP    5795840
#define OFF_W      7892992
#define OFF_XA     9990144
#define OFF_XB     10121216
#define OFF_EA     10252288
#define OFF_EB     10383360

#define MFMA3(ACC, AH, AL, BH, BL)                                              \
  ACC = __builtin_amdgcn_mfma_f32_16x16x32_bf16(AH, BH, ACC, 0, 0, 0);          \
  ACC = __builtin_amdgcn_mfma_f32_16x16x32_bf16(AH, BL, ACC, 0, 0, 0);          \
  ACC = __builtin_amdgcn_mfma_f32_16x16x32_bf16(AL, BH, ACC, 0, 0, 0);

__device__ __forceinline__ void split_bf16(float x, ushort_t& h, ushort_t& l) {
  __hip_bfloat16 bh = __float2bfloat16(x);
  h = *(ushort_t*)&bh;
  __hip_bfloat16 bl = __float2bfloat16(x - __bfloat162float(bh));
  l = *(ushort_t*)&bl;
}

// ---------------- reductions ----------------
__device__ __forceinline__ float wave_red_sum(float v) {
#pragma unroll
  for (int o = 32; o > 0; o >>= 1) v += __shfl_down(v, o);
  return v;
}
__device__ __forceinline__ float wave_red_max(float v) {
#pragma unroll
  for (int o = 32; o > 0; o >>= 1) v = fmaxf(v, __shfl_down(v, o));
  return v;
}
__device__ float blk_red_sum(float v) {
  __shared__ float sh[4];
  int lane = threadIdx.x & 63, wv = threadIdx.x >> 6;
  v = wave_red_sum(v);
  __syncthreads();
  if (lane == 0) sh[wv] = v;
  __syncthreads();
  return sh[0] + sh[1] + sh[2] + sh[3];
}
__device__ float blk_red_max(float v) {
  __shared__ float shm[4];
  int lane = threadIdx.x & 63, wv = threadIdx.x >> 6;
  v = wave_red_max(v);
  __syncthreads();
  if (lane == 0) shm[wv] = v;
  __syncthreads();
  return fmaxf(fmaxf(shm[0], shm[1]), fmaxf(shm[2], shm[3]));
}

// ---------------- prep: zero state + convert A and X to split-bf16 planes ----------------
__global__ __launch_bounds__(256) void k_prep(float* __restrict__ ws,
                                              const float* __restrict__ Are,
                                              const float* __restrict__ Aim,
                                              const float* __restrict__ Xre,
                                              const float* __restrict__ Xim,
                                              const float* __restrict__ gamma) {
  int bid = blockIdx.x, tid = threadIdx.x;
  if (bid < ZERO_FL / 256) {                       // zero R,G,q,d,v,u,up
    int idx = bid * 256 + tid;
    float v = 0.0f;
    if (idx < 131072 && (idx % 514) == 0) v = 0.01f;  // ridge on R diag (.x)
    ws[idx] = v;
  } else if (bid < ZERO_FL / 256 + (MM * LL) / 256) {  // A -> planes, sqrt(gamma) folded
    int idx = (bid - ZERO_FL / 256) * 256 + tid;
    ushort_t* dst = (ushort_t*)(ws + OFF_APL);
    float s = sqrtf(gamma[idx & (LL - 1)]);
    ushort_t h, l;
    split_bf16(Are[idx] * s, h, l);
    dst[idx] = h;
    dst[idx + MM * LL] = l;
    split_bf16(Aim[idx] * s, h, l);
    dst[idx + 2 * MM * LL] = h;
    dst[idx + 3 * MM * LL] = l;
  } else {                                          // X -> planes
    int idx = (bid - ZERO_FL / 256 - (MM * LL) / 256) * 256 + tid;
    ushort_t* dst = (ushort_t*)(ws + OFF_XPL);
    ushort_t h, l;
    split_bf16(Xre[idx], h, l);
    dst[idx] = h;
    dst[idx + MM * TT] = l;
    split_bf16(Xim[idx], h, l);
    dst[idx + 2 * MM * TT] = h;
    dst[idx + 3 * MM * TT] = l;
  }
}

// ---------------- MFMA gram tile (device fn) ----------------
__device__ void gram_tile(const ushort_t* __restrict__ pl, size_t PS, int K,
                          int kbeg, int kend, int tile, float* __restrict__ C) {
  const ushort_t* prh = pl;
  const ushort_t* prl = pl + PS;
  const ushort_t* pih = pl + 2 * PS;
  const ushort_t* pil = pl + 3 * PS;
  int i0 = (tile >> 2) * 64, j0 = (tile & 3) * 64;
  int lane = threadIdx.x & 63, wv = threadIdx.x >> 6;
  int m = i0 + wv * 16 + (lane & 15);
  int kq = (lane >> 4) * 8;
  f32x4 z = {0.f, 0.f, 0.f, 0.f};
  f32x4 Zrr[4], Zri[4], Zir[4], Zii[4];
#pragma unroll
  for (int s = 0; s < 4; ++s) { Zrr[s] = z; Zri[s] = z; Zir[s] = z; Zii[s] = z; }
  for (int k0 = kbeg; k0 < kend; k0 += 32) {
    size_t ao = (size_t)m * K + k0 + kq;
    bf16x8 arh = *(const bf16x8*)(prh + ao);
    bf16x8 arl = *(const bf16x8*)(prl + ao);
    bf16x8 aih = *(const bf16x8*)(pih + ao);
    bf16x8 ail = *(const bf16x8*)(pil + ao);
#pragma unroll
    for (int s = 0; s < 4; ++s) {
      size_t bo = (size_t)(j0 + s * 16 + (lane & 15)) * K + k0 + kq;
      bf16x8 brh = *(const bf16x8*)(prh + bo);
      bf16x8 brl = *(const bf16x8*)(prl + bo);
      bf16x8 bih = *(const bf16x8*)(pih + bo);
      bf16x8 bil = *(const bf16x8*)(pil + bo);
      MFMA3(Zrr[s], arh, arl, brh, brl);
      MFMA3(Zri[s], arh, arl, bih, bil);
      MFMA3(Zir[s], aih, ail, brh, brl);
      MFMA3(Zii[s], aih, ail, bih, bil);
    }
  }
  int rbase = i0 + wv * 16 + (lane >> 4) * 4;
#pragma unroll
  for (int s = 0; s < 4; ++s) {
    int col = j0 + s * 16 + (lane & 15);
#pragma unroll
    for (int r = 0; r < 4; ++r) {
      float re = Zrr[s][r] + Zii[s][r];   // a * conj(b)
      float im = Zir[s][r] - Zri[s][r];
      float* p = C + ((size_t)(rbase + r) * 256 + col) * 2;
      atomicAdd(p, re);
      atomicAdd(p + 1, im);
    }
  }
}

// ---------------- both grams in one launch ----------------
__global__ __launch_bounds__(256) void k_gram_both(float* __restrict__ ws) {
  int bid = blockIdx.x;
  if (bid < 256) {  // A-gram: 16 tiles x 16 K-splits, K=4096
    const ushort_t* pl = (const ushort_t*)(ws + OFF_APL);
    int tile = bid & 15, ks = bid >> 4;
    gram_tile(pl, (size_t)MM * LL, LL, ks * 256, ks * 256 + 256, tile, ws);
  } else {          // X-gram: 16 tiles x 8 K-splits, K=2048
    int b2 = bid - 256;
    const ushort_t* pl = (const ushort_t*)(ws + OFF_XPL);
    int tile = b2 & 15, ks = b2 >> 4;
    gram_tile(pl, (size_t)MM * TT, TT, ks * 256, ks * 256 + 256, tile, ws + OFF_G);
  }
}

// ---------------- mid: G -> bf16 planes  +  A^T -> bf16 planes ----------------
__global__ __launch_bounds__(256) void k_mid(float* __restrict__ ws,
                                             const float* __restrict__ Are,
                                             const float* __restrict__ Aim) {
  __shared__ float tr[32][33], ti[32][33];
  int bid = blockIdx.x, tid = threadIdx.x;
  if (bid < 256) {  // conv256: G -> Gp
    const float2* src = (const float2*)(ws + OFF_G);
    ushort_t* dst = (ushort_t*)(ws + OFF_GP);
    int idx = bid * 256 + tid;
    float2 v = src[idx];
    ushort_t h, l;
    split_bf16(v.x, h, l);
    dst[idx] = h;
    dst[idx + 65536] = l;
    split_bf16(v.y, h, l);
    dst[idx + 131072] = h;
    dst[idx + 196608] = l;
  } else {          // transpA: [256][4096] -> planes [4096][256]
    int b2 = bid - 256;
    ushort_t* dst = (ushort_t*)(ws + OFF_ATP);
    int c0 = (b2 & 127) * 32, r0 = (b2 >> 7) * 32;
    int tx = tid & 31, tg = tid >> 5;
#pragma unroll
    for (int i = 0; i < 4; ++i) {
      int r = tg + 8 * i;
      tr[r][tx] = Are[(size_t)(r0 + r) * LL + c0 + tx];
      ti[r][tx] = Aim[(size_t)(r0 + r) * LL + c0 + tx];
    }
    __syncthreads();
#pragma unroll
    for (int i = 0; i < 4; ++i) {
      int rr = tg + 8 * i;
      size_t o = (size_t)(c0 + rr) * 256 + r0 + tx;
      ushort_t h, l;
      split_bf16(tr[tx][rr], h, l);
      dst[o] = h;
      dst[o + 1048576] = l;
      split_bf16(ti[tx][rr], h, l);
      dst[o + 2097152] = h;
      dst[o + 3145728] = l;
    }
  }
}

// ---------------- Newton init (elementwise): E0 = I - D^-1 R ; X1 = (I+E0) D^-1 ----------------
__global__ __launch_bounds__(256) void k_newt_init(float* __restrict__ ws) {
  const float2* R = (const float2*)ws;
  float2* E = (float2*)(ws + OFF_EA);
  float2* X = (float2*)(ws + OFF_XA);
  int idx = blockIdx.x * 256 + threadIdx.x;
  int i = idx >> 8, j = idx & 255;
  float Dii = R[i * 257].x;
  float Djj = R[j * 257].x;
  float2 r = R[idx];
  float dl = (i == j) ? 1.0f : 0.0f;
  float ex = dl - r.x / Dii;
  float ey = -r.y / Dii;
  E[idx] = make_float2(ex, ey);
  X[idx] = make_float2((dl + ex) / Djj, ey / Djj);
}

// ---------------- coupled Newton step ----------------
// blocks [0,xblocks): Xout = Xin + Ein@Xin ; blocks [xblocks,...): Eout = Ein@Ein
__global__ __launch_bounds__(256) void k_newt_step(const float2* __restrict__ Xin,
                                                   const float2* __restrict__ Ein,
                                                   float2* __restrict__ Xout,
                                                   float2* __restrict__ Eout, int xblocks) {
  __shared__ float2 As[16][17], Bs[16][17];
  int bid = blockIdx.x;
  bool isX = bid < xblocks;
  int b = isX ? bid : bid - xblocks;
  const float2* Bm = isX ? Xin : Ein;
  int i0 = (b >> 4) * 16, j0 = (b & 15) * 16;
  int tx = threadIdx.x & 15, ty = threadIdx.x >> 4;
  float accx = 0.f, accy = 0.f;
  for (int k0 = 0; k0 < 256; k0 += 16) {
    __syncthreads();
    As[ty][tx] = Ein[(i0 + ty) * 256 + k0 + tx];
    Bs[ty][tx] = Bm[(k0 + ty) * 256 + j0 + tx];
    __syncthreads();
#pragma unroll
    for (int kk = 0; kk < 16; ++kk) {
      float2 a = As[ty][kk], bb = Bs[kk][tx];
      accx += a.x * bb.x - a.y * bb.y;
      accy += a.x * bb.y + a.y * bb.x;
    }
  }
  int idx = (i0 + ty) * 256 + j0 + tx;
  if (isX) {
    float2 x = Xin[idx];
    Xout[idx] = make_float2(x.x + accx, x.y + accy);
  } else {
    Eout[idx] = make_float2(accx, accy);
  }
}

// ---------------- Newton final: X' = Xin + Ein@Xin -> split-bf16 planes ----------------
__global__ __launch_bounds__(256) void k_newt_fin(const float2* __restrict__ Xin,
                                                  const float2* __restrict__ Ein,
                                                  ushort_t* __restrict__ dst) {
  __shared__ float2 As[16][17], Bs[16][17];
  int b = blockIdx.x;
  int i0 = (b >> 4) * 16, j0 = (b & 15) * 16;
  int tx = threadIdx.x & 15, ty = threadIdx.x >> 4;
  float accx = 0.f, accy = 0.f;
  for (int k0 = 0; k0 < 256; k0 += 16) {
    __syncthreads();
    As[ty][tx] = Ein[(i0 + ty) * 256 + k0 + tx];
    Bs[ty][tx] = Xin[(k0 + ty) * 256 + j0 + tx];
    __syncthreads();
#pragma unroll
    for (int kk = 0; kk < 16; ++kk) {
      float2 a = As[ty][kk], bb = Bs[kk][tx];
      accx += a.x * bb.x - a.y * bb.y;
      accy += a.x * bb.y + a.y * bb.x;
    }
  }
  int idx = (i0 + ty) * 256 + j0 + tx;
  float2 x = Xin[idx];
  float vx = x.x + accx, vy = x.y + accy;
  ushort_t h, l;
  split_bf16(vx, h, l);
  dst[idx] = h;
  dst[idx + 65536] = l;
  split_bf16(vy, h, l);
  dst[idx + 131072] = h;
  dst[idx + 196608] = l;
}

// ---------------- wide MFMA: C[256x4096] = A(256x256) @ B(256x4096) ----------------
// mode 0: Cout=W write + d[l] atomics; mode 1: q[l] atomics (Wf = W fp32)
__global__ __launch_bounds__(256) void k_wide_mfma(const ushort_t* __restrict__ Ap,
                                                   const ushort_t* __restrict__ Bp,
                                                   const float* __restrict__ AuxRe,
                                                   const float* __restrict__ AuxIm,
                                                   const float2* __restrict__ Wf,
                                                   float2* __restrict__ Cout,
                                                   float* __restrict__ dq, int mode) {
  const ushort_t* arh_p = Ap;
  const ushort_t* arl_p = Ap + 65536;
  const ushort_t* aih_p = Ap + 131072;
  const ushort_t* ail_p = Ap + 196608;
  const ushort_t* brh_p = Bp;
  const ushort_t* brl_p = Bp + 1048576;
  const ushort_t* bih_p = Bp + 2097152;
  const ushort_t* bil_p = Bp + 3145728;
  int j0 = blockIdx.x * 64;  // l
  int i0 = blockIdx.y * 64;  // m
  int lane = threadIdx.x & 63, wv = threadIdx.x >> 6;
  int m = i0 + wv * 16 + (lane & 15);
  int kq = (lane >> 4) * 8;
  f32x4 z = {0.f, 0.f, 0.f, 0.f};
  f32x4 Zrr[4], Zri[4], Zir[4], Zii[4];
#pragma unroll
  for (int s = 0; s < 4; ++s) { Zrr[s] = z; Zri[s] = z; Zir[s] = z; Zii[s] = z; }
  for (int k0 = 0; k0 < 256; k0 += 32) {
    size_t ao = (size_t)m * 256 + k0 + kq;
    bf16x8 arh = *(const bf16x8*)(arh_p + ao);
    bf16x8 arl = *(const bf16x8*)(arl_p + ao);
    bf16x8 aih = *(const bf16x8*)(aih_p + ao);
    bf16x8 ail = *(const bf16x8*)(ail_p + ao);
#pragma unroll
    for (int s = 0; s < 4; ++s) {
      size_t bo = (size_t)(j0 + s * 16 + (lane & 15)) * 256 + k0 + kq;
      bf16x8 brh = *(const bf16x8*)(brh_p + bo);
      bf16x8 brl = *(const bf16x8*)(brl_p + bo);
      bf16x8 bih = *(const bf16x8*)(bih_p + bo);
      bf16x8 bil = *(const bf16x8*)(bil_p + bo);
      MFMA3(Zrr[s], arh, arl, brh, brl);
      MFMA3(Zri[s], arh, arl, bih, bil);
      MFMA3(Zir[s], aih, ail, brh, brl);
      MFMA3(Zii[s], aih, ail, bih, bil);
    }
  }
  int rbase = i0 + wv * 16 + (lane >> 4) * 4;
#pragma unroll
  for (int s = 0; s < 4; ++s) {
    int col = j0 + s * 16 + (lane & 15);
    float part = 0.f;
#pragma unroll
    for (int r = 0; r < 4; ++r) {
      float re = Zrr[s][r] - Zii[s][r];   // a * b
      float im = Zri[s][r] + Zir[s][r];
      size_t o = (size_t)(rbase + r) * LL + col;
      if (mode == 0) {
        Cout[o] = make_float2(re, im);
        part += re * AuxRe[o] - im * AuxIm[o];
      } else {
        float2 w = Wf[o];
        part += w.x * re + w.y * im;
      }
    }
    part += __shfl_down(part, 32);
    part += __shfl_down(part, 16);
    if ((lane >> 4) == 0) atomicAdd(dq + col, part);
  }
}

// ---------------- transpose W float2 [256][4096] -> split-bf16 planes [4096][256] ------
__global__ __launch_bounds__(256) void k_transpW(const float2* __restrict__ W,
                                                 ushort_t* __restrict__ dst) {
  __shared__ float tr[32][33], ti[32][33];
  int c0 = blockIdx.x * 32, r0 = blockIdx.y * 32;
  int tx = threadIdx.x & 31, tg = threadIdx.x >> 5;
#pragma unroll
  for (int i = 0; i < 4; ++i) {
    int r = tg + 8 * i;
    float2 w = W[(size_t)(r0 + r) * LL + c0 + tx];
    tr[r][tx] = w.x;
    ti[r][tx] = w.y;
  }
  __syncthreads();
#pragma unroll
  for (int i = 0; i < 4; ++i) {
    int rr = tg + 8 * i;
    size_t o = (size_t)(c0 + rr) * 256 + r0 + tx;
    ushort_t h, l;
    split_bf16(tr[tx][rr], h, l);
    dst[o] = h;
    dst[o + 1048576] = l;
    split_bf16(ti[tx][rr], h, l);
    dst[o + 2097152] = h;
    dst[o + 3145728] = l;
  }
}

// ---------------- v,u + LayerNorm (single block) ----------------
__global__ __launch_bounds__(256) void k_uvln(float* __restrict__ ws,
                                              const float* __restrict__ gamma,
                                              const float* __restrict__ delta,
                                              const float* __restrict__ lnw,
                                              const float* __restrict__ lnb) {
  const float* q = ws + OFF_Q;
  const float* d = ws + OFF_D;
  float* vvec = ws + OFF_V;
  float* uvec = ws + OFF_U;
  float* up = ws + OFF_UP;
  int tid = threadIdx.x;
  float dlt = 1.0f / (1.0f + expf(-delta[0]));
  float s = 0.f;
  for (int i = tid; i < LL; i += 256) {
    float v = q[i] / (d[i] + 1e-12f);
    float p = gamma[i];
    float u = p + dlt * (v - p);
    vvec[i] = v;
    uvec[i] = u;
    s += u;
  }
  float mu = blk_red_sum(s) * (1.0f / LL);
  float s2 = 0.f;
  for (int i = tid; i < LL; i += 256) { float dd = uvec[i] - mu; s2 += dd * dd; }
  float var = blk_red_sum(s2) * (1.0f / LL);
  float inv = rsqrtf(var + 1e-5f);
  for (int i = tid; i < LL; i += 256) up[i] = (uvec[i] - mu) * inv * lnw[i] + lnb[i];
}

// ---------------- gate row + attention row + final combine ----------------
__global__ __launch_bounds__(256) void k_gateattn(const float* __restrict__ ws,
                                                  const float* __restrict__ Wg,
                                                  const float* __restrict__ gb,
                                                  const float* __restrict__ inw,
                                                  const float* __restrict__ inb,
                                                  const float* __restrict__ outw,
                                                  const float* __restrict__ outb,
                                                  const float* __restrict__ gamma,
                                                  const float* __restrict__ lmbda,
                                                  float* __restrict__ out) {
  const float* uvec = ws + OFF_U;
  const float* up = ws + OFF_UP;
  const float* vvec = ws + OFF_V;
  int i = blockIdx.x, tid = threadIdx.x;
  const float4* wr = (const float4*)(Wg + (size_t)i * LL);
  const float4* u4 = (const float4*)uvec;
  float s = 0.f;
  for (int j = tid; j < LL / 4; j += 256) {
    float4 w = wr[j], x = u4[j];
    s += w.x * x.x + w.y * x.y + w.z * x.z + w.w * x.w;
  }
  float tot = blk_red_sum(s);
  float g = 1.0f / (1.0f + expf(-(tot + gb[i])));
  float qv = up[i] * inw[0] + inb[0];
  float w1 = inw[1], b1 = inb[1], w2 = inw[2], b2 = inb[2];
  const float4* up4 = (const float4*)up;
  float mx = -3.4e38f;
  for (int j = tid; j < LL / 4; j += 256) {
    float4 u = up4[j];
    mx = fmaxf(mx, fmaxf(fmaxf(qv * (u.x * w1 + b1), qv * (u.y * w1 + b1)),
                         fmaxf(qv * (u.z * w1 + b1), qv * (u.w * w1 + b1))));
  }
  mx = blk_red_max(mx);
  float den = 0.f, num = 0.f;
  for (int j = tid; j < LL / 4; j += 256) {
    float4 u = up4[j];
    float e0 = expf(qv * (u.x * w1 + b1) - mx);
    float e1 = expf(qv * (u.y * w1 + b1) - mx);
    float e2 = expf(qv * (u.z * w1 + b1) - mx);
    float e3 = expf(qv * (u.w * w1 + b1) - mx);
    den += e0 + e1 + e2 + e3;
    num += e0 * (u.x * w2 + b2) + e1 * (u.y * w2 + b2) + e2 * (u.z * w2 + b2) + e3 * (u.w * w2 + b2);
  }
  den = blk_red_sum(den);
  num = blk_red_sum(num);
  if (tid == 0) {
    float attn = (num / den) * outw[0] + outb[0];
    float r = g * vvec[i] + (1.0f - g) * gamma[i] + attn - lmbda[0];
    out[i] = fmaxf(r, 0.0f);
  }
}

extern "C" void kernel_launch(void* const* d_in, const int* in_sizes, int n_in,
                              void* d_out, int out_size, void* d_ws, size_t ws_size,
                              hipStream_t stream) {
  const float* gamma = (const float*)d_in[0];
  const float* Are   = (const float*)d_in[1];
  const float* Aim   = (const float*)d_in[2];
  const float* Xre   = (const float*)d_in[3];
  const float* Xim   = (const float*)d_in[4];
  const float* lnw   = (const float*)d_in[5];
  const float* lnb   = (const float*)d_in[6];
  const float* inw   = (const float*)d_in[7];
  const float* inb   = (const float*)d_in[8];
  const float* outw  = (const float*)d_in[9];
  const float* outb  = (const float*)d_in[10];
  const float* gateW = (const float*)d_in[11];
  const float* gateb = (const float*)d_in[12];
  const float* delta = (const float*)d_in[13];
  const float* lmbda = (const float*)d_in[14];
  float* out = (float*)d_out;
  float* ws = (float*)d_ws;

  float2* XA = (float2*)(ws + OFF_XA);
  float2* XB = (float2*)(ws + OFF_XB);
  float2* EA = (float2*)(ws + OFF_EA);
  float2* EB = (float2*)(ws + OFF_EB);
  ushort_t* Rinvp = (ushort_t*)(ws + OFF_RINVP);
  float2* W = (float2*)(ws + OFF_W);

  int prep_blocks = ZERO_FL / 256 + (MM * LL) / 256 + (MM * TT) / 256;
  k_prep<<<prep_blocks, 256, 0, stream>>>(ws, Are, Aim, Xre, Xim, gamma);
  k_gram_both<<<384, 256, 0, stream>>>(ws);
  k_mid<<<1280, 256, 0, stream>>>(ws, Are, Aim);

  // Newton-Schulz via coupled residual iteration: E=I-XR; X'=(I+E)X, E'=E^2.
  k_newt_init<<<256, 256, 0, stream>>>(ws);                       // X1->XA, E0->EA
  k_newt_step<<<256, 256, 0, stream>>>(XA, EA, XB, EB, 0);        // E1->EB
  k_newt_step<<<512, 256, 0, stream>>>(XA, EB, XB, EA, 256);      // X2->XB, E2->EA
  k_newt_step<<<512, 256, 0, stream>>>(XB, EA, XA, EB, 256);      // X3->XA, E3->EB
  k_newt_step<<<512, 256, 0, stream>>>(XA, EB, XB, EA, 256);      // X4->XB, E4->EA
  k_newt_step<<<512, 256, 0, stream>>>(XB, EA, XA, EB, 256);      // X5->XA, E5->EB
  k_newt_fin<<<256, 256, 0, stream>>>(XA, EB, Rinvp);             // X6 -> planes

  k_wide_mfma<<<dim3(64, 4), 256, 0, stream>>>(Rinvp, (ushort_t*)(ws + OFF_ATP),
                                               Are, Aim, nullptr, W, ws + OFF_D, 0);
  k_transpW<<<dim3(128, 8), 256, 0, stream>>>(W, (ushort_t*)(ws + OFF_WTP));
  k_wide_mfma<<<dim3(64, 4), 256, 0, stream>>>((ushort_t*)(ws + OFF_GP),
                                               (ushort_t*)(ws + OFF_WTP),
                                               nullptr, nullptr, W, nullptr, ws + OFF_Q, 1);
  k_uvln<<<1, 256, 0, stream>>>(ws, gamma, delta, lnw, lnb);
  k_gateattn<<<LL, 256, 0, stream>>>(ws, gateW, gateb, inw, inb, outw, outb, gamma, lmbda, out);
}

// Round 7
// 321.973 us; speedup vs baseline: 3.7412x; 1.1081x over previous
//
#include <hip/hip_runtime.h>
#include <hip/hip_bf16.h>
#include <math.h>

#define MM 256
#define LL 4096
#define TT 2048

typedef __attribute__((ext_vector_type(8))) short bf16x8;
typedef __attribute__((ext_vector_type(4))) float f32x4;
typedef __attribute__((ext_vector_type(4))) unsigned short us4;
typedef unsigned short ushort_t;

// workspace float offsets
#define OFF_G      131072
#define OFF_Q      262144
#define OFF_D      266240
#define OFF_V      270336
#define OFF_U      274432
#define OFF_UP     278528
#define ZERO_FL    290816   // zero range [0, ZERO_FL)
#define OFF_RINVP  290816
#define OFF_GP     421888
#define OFF_APL    552960
#define OFF_XPL    2650112
#define OFF_ATP    3698688
#define OFF_WTP    5795840
#define OFF_XA     9990144
#define OFF_XB     10121216
#define OFF_EA     10252288
#define OFF_EB     10383360

#define MFMA3(ACC, AH, AL, BH, BL)                                              \
  ACC = __builtin_amdgcn_mfma_f32_16x16x32_bf16(AH, BH, ACC, 0, 0, 0);          \
  ACC = __builtin_amdgcn_mfma_f32_16x16x32_bf16(AH, BL, ACC, 0, 0, 0);          \
  ACC = __builtin_amdgcn_mfma_f32_16x16x32_bf16(AL, BH, ACC, 0, 0, 0);

__device__ __forceinline__ void split_bf16(float x, ushort_t& h, ushort_t& l) {
  __hip_bfloat16 bh = __float2bfloat16(x);
  h = *(ushort_t*)&bh;
  __hip_bfloat16 bl = __float2bfloat16(x - __bfloat162float(bh));
  l = *(ushort_t*)&bl;
}
__device__ __forceinline__ float bfu2f(ushort_t u) {
  unsigned v = ((unsigned)u) << 16;
  float f;
  __builtin_memcpy(&f, &v, 4);
  return f;
}

// ---------------- reductions ----------------
__device__ __forceinline__ float wave_red_sum(float v) {
#pragma unroll
  for (int o = 32; o > 0; o >>= 1) v += __shfl_down(v, o);
  return v;
}
__device__ __forceinline__ float wave_red_max(float v) {
#pragma unroll
  for (int o = 32; o > 0; o >>= 1) v = fmaxf(v, __shfl_down(v, o));
  return v;
}
__device__ float blk_red_sum(float v) {
  __shared__ float sh[4];
  int lane = threadIdx.x & 63, wv = threadIdx.x >> 6;
  v = wave_red_sum(v);
  __syncthreads();
  if (lane == 0) sh[wv] = v;
  __syncthreads();
  return sh[0] + sh[1] + sh[2] + sh[3];
}
__device__ float blk_red_max(float v) {
  __shared__ float shm[4];
  int lane = threadIdx.x & 63, wv = threadIdx.x >> 6;
  v = wave_red_max(v);
  __syncthreads();
  if (lane == 0) shm[wv] = v;
  __syncthreads();
  return fmaxf(fmaxf(shm[0], shm[1]), fmaxf(shm[2], shm[3]));
}

// ---------------- prep: zero state + convert A and X to split-bf16 planes ----------------
__global__ __launch_bounds__(256) void k_prep(float* __restrict__ ws,
                                              const float* __restrict__ Are,
                                              const float* __restrict__ Aim,
                                              const float* __restrict__ Xre,
                                              const float* __restrict__ Xim,
                                              const float* __restrict__ gamma) {
  int bid = blockIdx.x, tid = threadIdx.x;
  if (bid < ZERO_FL / 256) {                       // zero R,G,q,d,v,u,up
    int idx = bid * 256 + tid;
    float v = 0.0f;
    if (idx < 131072 && (idx % 514) == 0) v = 0.01f;  // ridge on R diag (.x)
    ws[idx] = v;
  } else if (bid < ZERO_FL / 256 + (MM * LL) / 256) {  // A -> planes, sqrt(gamma) folded
    int idx = (bid - ZERO_FL / 256) * 256 + tid;
    ushort_t* dst = (ushort_t*)(ws + OFF_APL);
    float s = sqrtf(gamma[idx & (LL - 1)]);
    ushort_t h, l;
    split_bf16(Are[idx] * s, h, l);
    dst[idx] = h;
    dst[idx + MM * LL] = l;
    split_bf16(Aim[idx] * s, h, l);
    dst[idx + 2 * MM * LL] = h;
    dst[idx + 3 * MM * LL] = l;
  } else {                                          // X -> planes
    int idx = (bid - ZERO_FL / 256 - (MM * LL) / 256) * 256 + tid;
    ushort_t* dst = (ushort_t*)(ws + OFF_XPL);
    ushort_t h, l;
    split_bf16(Xre[idx], h, l);
    dst[idx] = h;
    dst[idx + MM * TT] = l;
    split_bf16(Xim[idx], h, l);
    dst[idx + 2 * MM * TT] = h;
    dst[idx + 3 * MM * TT] = l;
  }
}

// ---------------- gram v3: LDS-staged, Hermitian lower tiles only ----------------
// A-gram: blocks [0,320): tile=bid%10, ksplit=bid/10 (Kc=128, K=4096) -> R (ws)
// X-gram: blocks [320,480): tile=b2%10, ksplit=b2/10 (Kc=128, K=2048) -> G (ws+OFF_G)
__global__ __launch_bounds__(256, 4) void k_gram_both(float* __restrict__ ws) {
  __shared__ __align__(16) ushort_t sA[4][64][40];
  __shared__ __align__(16) ushort_t sB[4][64][40];
  const int ti_lu[10] = {0, 1, 1, 2, 2, 2, 3, 3, 3, 3};
  const int tj_lu[10] = {0, 0, 1, 0, 1, 2, 0, 1, 2, 3};
  int bid = blockIdx.x;
  const ushort_t* pl;
  float* C;
  int K, tile, ksplit;
  size_t PS;
  if (bid < 320) {
    pl = (const ushort_t*)(ws + OFF_APL);
    C = ws;
    K = LL;
    PS = (size_t)MM * LL;
    tile = bid % 10;
    ksplit = bid / 10;
  } else {
    int b2 = bid - 320;
    pl = (const ushort_t*)(ws + OFF_XPL);
    C = ws + OFF_G;
    K = TT;
    PS = (size_t)MM * TT;
    tile = b2 % 10;
    ksplit = b2 / 10;
  }
  int kbeg = ksplit * 128;
  int i0 = ti_lu[tile] * 64, j0 = tj_lu[tile] * 64;
  bool diag = (i0 == j0);
  int tid = threadIdx.x;
  int lane = tid & 63, wv = tid >> 6;
  int srow = tid >> 2, sslot = tid & 3;
  int arow = wv * 16 + (lane & 15);
  int kq = (lane >> 4) * 8;
  f32x4 z = {0.f, 0.f, 0.f, 0.f};
  f32x4 Zrr[4], Zri[4], Zir[4], Zii[4];
#pragma unroll
  for (int s = 0; s < 4; ++s) { Zrr[s] = z; Zri[s] = z; Zir[s] = z; Zii[s] = z; }

  for (int chunk = 0; chunk < 4; ++chunk) {
    int k0 = kbeg + chunk * 32;
    __syncthreads();
#pragma unroll
    for (int p = 0; p < 4; ++p) {
      *(bf16x8*)&sA[p][srow][sslot * 8] =
          *(const bf16x8*)(pl + p * PS + (size_t)(i0 + srow) * K + k0 + sslot * 8);
      if (!diag)
        *(bf16x8*)&sB[p][srow][sslot * 8] =
            *(const bf16x8*)(pl + p * PS + (size_t)(j0 + srow) * K + k0 + sslot * 8);
    }
    __syncthreads();
    bf16x8 arh = *(const bf16x8*)&sA[0][arow][kq];
    bf16x8 arl = *(const bf16x8*)&sA[1][arow][kq];
    bf16x8 aih = *(const bf16x8*)&sA[2][arow][kq];
    bf16x8 ail = *(const bf16x8*)&sA[3][arow][kq];
    ushort_t(*bs)[64][40] = diag ? sA : sB;
#pragma unroll
    for (int s = 0; s < 4; ++s) {
      int brow = s * 16 + (lane & 15);
      bf16x8 brh = *(const bf16x8*)&bs[0][brow][kq];
      bf16x8 brl = *(const bf16x8*)&bs[1][brow][kq];
      bf16x8 bih = *(const bf16x8*)&bs[2][brow][kq];
      bf16x8 bil = *(const bf16x8*)&bs[3][brow][kq];
      MFMA3(Zrr[s], arh, arl, brh, brl);
      MFMA3(Zri[s], arh, arl, bih, bil);
      MFMA3(Zir[s], aih, ail, brh, brl);
      MFMA3(Zii[s], aih, ail, bih, bil);
    }
  }
  int rbase = i0 + wv * 16 + (lane >> 4) * 4;
#pragma unroll
  for (int s = 0; s < 4; ++s) {
    int col = j0 + s * 16 + (lane & 15);
#pragma unroll
    for (int r = 0; r < 4; ++r) {
      float re = Zrr[s][r] + Zii[s][r];   // a * conj(b)
      float im = Zir[s][r] - Zri[s][r];
      float* p = C + ((size_t)(rbase + r) * 256 + col) * 2;
      atomicAdd(p, re);
      atomicAdd(p + 1, im);
    }
  }
}

// ---------------- mid: G (mirror) -> bf16 planes  +  A^T -> bf16 planes ----------------
__global__ __launch_bounds__(256) void k_mid(float* __restrict__ ws,
                                             const float* __restrict__ Are,
                                             const float* __restrict__ Aim) {
  __shared__ float tr[32][33], ti[32][33];
  int bid = blockIdx.x, tid = threadIdx.x;
  if (bid < 256) {  // conv256 with Hermitian mirror: G -> Gp
    const float2* src = (const float2*)(ws + OFF_G);
    ushort_t* dst = (ushort_t*)(ws + OFF_GP);
    int idx = bid * 256 + tid;
    int i = idx >> 8, j = idx & 255;
    float2 v;
    if ((i >> 6) >= (j >> 6)) {
      v = src[idx];
    } else {
      v = src[j * 256 + i];
      v.y = -v.y;
    }
    ushort_t h, l;
    split_bf16(v.x, h, l);
    dst[idx] = h;
    dst[idx + 65536] = l;
    split_bf16(v.y, h, l);
    dst[idx + 131072] = h;
    dst[idx + 196608] = l;
  } else {          // transpA: [256][4096] -> planes [4096][256]
    int b2 = bid - 256;
    ushort_t* dst = (ushort_t*)(ws + OFF_ATP);
    int c0 = (b2 & 127) * 32, r0 = (b2 >> 7) * 32;
    int tx = tid & 31, tg = tid >> 5;
#pragma unroll
    for (int i = 0; i < 4; ++i) {
      int r = tg + 8 * i;
      tr[r][tx] = Are[(size_t)(r0 + r) * LL + c0 + tx];
      ti[r][tx] = Aim[(size_t)(r0 + r) * LL + c0 + tx];
    }
    __syncthreads();
#pragma unroll
    for (int i = 0; i < 4; ++i) {
      int rr = tg + 8 * i;
      size_t o = (size_t)(c0 + rr) * 256 + r0 + tx;
      ushort_t h, l;
      split_bf16(tr[tx][rr], h, l);
      dst[o] = h;
      dst[o + 1048576] = l;
      split_bf16(ti[tx][rr], h, l);
      dst[o + 2097152] = h;
      dst[o + 3145728] = l;
    }
  }
}

// ---------------- Newton init (elementwise, R mirror): E0 = I - D^-1 R ; X1 = (I+E0) D^-1 ---
__global__ __launch_bounds__(256) void k_newt_init(float* __restrict__ ws) {
  const float2* R = (const float2*)ws;
  float2* E = (float2*)(ws + OFF_EA);
  float2* X = (float2*)(ws + OFF_XA);
  int idx = blockIdx.x * 256 + threadIdx.x;
  int i = idx >> 8, j = idx & 255;
  float Dii = R[i * 257].x;
  float Djj = R[j * 257].x;
  float2 r;
  if ((i >> 6) >= (j >> 6)) {
    r = R[idx];
  } else {
    r = R[j * 256 + i];
    r.y = -r.y;
  }
  float dl = (i == j) ? 1.0f : 0.0f;
  float ex = dl - r.x / Dii;
  float ey = -r.y / Dii;
  E[idx] = make_float2(ex, ey);
  X[idx] = make_float2((dl + ex) / Djj, ey / Djj);
}

// ---------------- coupled Newton step ----------------
// blocks [0,xblocks): Xout = Xin + Ein@Xin ; blocks [xblocks,...): Eout = Ein@Ein
__global__ __launch_bounds__(256) void k_newt_step(const float2* __restrict__ Xin,
                                                   const float2* __restrict__ Ein,
                                                   float2* __restrict__ Xout,
                                                   float2* __restrict__ Eout, int xblocks) {
  __shared__ float2 As[16][17], Bs[16][17];
  int bid = blockIdx.x;
  bool isX = bid < xblocks;
  int b = isX ? bid : bid - xblocks;
  const float2* Bm = isX ? Xin : Ein;
  int i0 = (b >> 4) * 16, j0 = (b & 15) * 16;
  int tx = threadIdx.x & 15, ty = threadIdx.x >> 4;
  float accx = 0.f, accy = 0.f;
  for (int k0 = 0; k0 < 256; k0 += 16) {
    __syncthreads();
    As[ty][tx] = Ein[(i0 + ty) * 256 + k0 + tx];
    Bs[ty][tx] = Bm[(k0 + ty) * 256 + j0 + tx];
    __syncthreads();
#pragma unroll
    for (int kk = 0; kk < 16; ++kk) {
      float2 a = As[ty][kk], bb = Bs[kk][tx];
      accx += a.x * bb.x - a.y * bb.y;
      accy += a.x * bb.y + a.y * bb.x;
    }
  }
  int idx = (i0 + ty) * 256 + j0 + tx;
  if (isX) {
    float2 x = Xin[idx];
    Xout[idx] = make_float2(x.x + accx, x.y + accy);
  } else {
    Eout[idx] = make_float2(accx, accy);
  }
}

// ---------------- Newton final: X' = Xin + Ein@Xin -> split-bf16 planes ----------------
__global__ __launch_bounds__(256) void k_newt_fin(const float2* __restrict__ Xin,
                                                  const float2* __restrict__ Ein,
                                                  ushort_t* __restrict__ dst) {
  __shared__ float2 As[16][17], Bs[16][17];
  int b = blockIdx.x;
  int i0 = (b >> 4) * 16, j0 = (b & 15) * 16;
  int tx = threadIdx.x & 15, ty = threadIdx.x >> 4;
  float accx = 0.f, accy = 0.f;
  for (int k0 = 0; k0 < 256; k0 += 16) {
    __syncthreads();
    As[ty][tx] = Ein[(i0 + ty) * 256 + k0 + tx];
    Bs[ty][tx] = Xin[(k0 + ty) * 256 + j0 + tx];
    __syncthreads();
#pragma unroll
    for (int kk = 0; kk < 16; ++kk) {
      float2 a = As[ty][kk], bb = Bs[kk][tx];
      accx += a.x * bb.x - a.y * bb.y;
      accy += a.x * bb.y + a.y * bb.x;
    }
  }
  int idx = (i0 + ty) * 256 + j0 + tx;
  float2 x = Xin[idx];
  float vx = x.x + accx, vy = x.y + accy;
  ushort_t h, l;
  split_bf16(vx, h, l);
  dst[idx] = h;
  dst[idx + 65536] = l;
  split_bf16(vy, h, l);
  dst[idx + 131072] = h;
  dst[idx + 196608] = l;
}

// ---------------- wide MFMA: (256x256) @ (256x4096) ----------------
// mode 0: write W^T split-bf16 planes (WTout) + d[l] atomics (AuxRe/AuxIm = A fp32)
// mode 1: Bp = W^T planes; q[l] atomics (W reconstructed from Bp h+l)
__global__ __launch_bounds__(256) void k_wide_mfma(const ushort_t* __restrict__ Ap,
                                                   const ushort_t* __restrict__ Bp,
                                                   const float* __restrict__ AuxRe,
                                                   const float* __restrict__ AuxIm,
                                                   ushort_t* __restrict__ WTout,
                                                   float* __restrict__ dq, int mode) {
  const ushort_t* arh_p = Ap;
  const ushort_t* arl_p = Ap + 65536;
  const ushort_t* aih_p = Ap + 131072;
  const ushort_t* ail_p = Ap + 196608;
  const ushort_t* brh_p = Bp;
  const ushort_t* brl_p = Bp + 1048576;
  const ushort_t* bih_p = Bp + 2097152;
  const ushort_t* bil_p = Bp + 3145728;
  int j0 = blockIdx.x * 64;  // l
  int i0 = blockIdx.y * 64;  // m
  int lane = threadIdx.x & 63, wv = threadIdx.x >> 6;
  int m = i0 + wv * 16 + (lane & 15);
  int kq = (lane >> 4) * 8;
  f32x4 z = {0.f, 0.f, 0.f, 0.f};
  f32x4 Zrr[4], Zri[4], Zir[4], Zii[4];
#pragma unroll
  for (int s = 0; s < 4; ++s) { Zrr[s] = z; Zri[s] = z; Zir[s] = z; Zii[s] = z; }
  for (int k0 = 0; k0 < 256; k0 += 32) {
    size_t ao = (size_t)m * 256 + k0 + kq;
    bf16x8 arh = *(const bf16x8*)(arh_p + ao);
    bf16x8 arl = *(const bf16x8*)(arl_p + ao);
    bf16x8 aih = *(const bf16x8*)(aih_p + ao);
    bf16x8 ail = *(const bf16x8*)(ail_p + ao);
#pragma unroll
    for (int s = 0; s < 4; ++s) {
      size_t bo = (size_t)(j0 + s * 16 + (lane & 15)) * 256 + k0 + kq;
      bf16x8 brh = *(const bf16x8*)(brh_p + bo);
      bf16x8 brl = *(const bf16x8*)(brl_p + bo);
      bf16x8 bih = *(const bf16x8*)(bih_p + bo);
      bf16x8 bil = *(const bf16x8*)(bil_p + bo);
      MFMA3(Zrr[s], arh, arl, brh, brl);
      MFMA3(Zri[s], arh, arl, bih, bil);
      MFMA3(Zir[s], aih, ail, brh, brl);
      MFMA3(Zii[s], aih, ail, bih, bil);
    }
  }
  int rbase = i0 + wv * 16 + (lane >> 4) * 4;
#pragma unroll
  for (int s = 0; s < 4; ++s) {
    int col = j0 + s * 16 + (lane & 15);
    size_t wo = (size_t)col * 256 + rbase;
    float part = 0.f;
    if (mode == 0) {
      us4 hr, lr, hi, li;
#pragma unroll
      for (int r = 0; r < 4; ++r) {
        float re = Zrr[s][r] - Zii[s][r];   // a * b
        float im = Zri[s][r] + Zir[s][r];
        ushort_t h, l;
        split_bf16(re, h, l);
        hr[r] = h; lr[r] = l;
        split_bf16(im, h, l);
        hi[r] = h; li[r] = l;
        size_t o = (size_t)(rbase + r) * LL + col;
        part += re * AuxRe[o] - im * AuxIm[o];
      }
      *(us4*)(WTout + wo) = hr;
      *(us4*)(WTout + 1048576 + wo) = lr;
      *(us4*)(WTout + 2097152 + wo) = hi;
      *(us4*)(WTout + 3145728 + wo) = li;
    } else {
      us4 wh = *(const us4*)(brh_p + wo);
      us4 wl = *(const us4*)(brl_p + wo);
      us4 wih = *(const us4*)(bih_p + wo);
      us4 wil = *(const us4*)(bil_p + wo);
#pragma unroll
      for (int r = 0; r < 4; ++r) {
        float re = Zrr[s][r] - Zii[s][r];
        float im = Zri[s][r] + Zir[s][r];
        float wx = bfu2f(wh[r]) + bfu2f(wl[r]);
        float wy = bfu2f(wih[r]) + bfu2f(wil[r]);
        part += wx * re + wy * im;
      }
    }
    part += __shfl_down(part, 32);
    part += __shfl_down(part, 16);
    if ((lane >> 4) == 0) atomicAdd(dq + col, part);
  }
}

// ---------------- v,u + LayerNorm (single block) ----------------
__global__ __launch_bounds__(256) void k_uvln(float* __restrict__ ws,
                                              const float* __restrict__ gamma,
                                              const float* __restrict__ delta,
                                              const float* __restrict__ lnw,
                                              const float* __restrict__ lnb) {
  const float* q = ws + OFF_Q;
  const float* d = ws + OFF_D;
  float* vvec = ws + OFF_V;
  float* uvec = ws + OFF_U;
  float* up = ws + OFF_UP;
  int tid = threadIdx.x;
  float dlt = 1.0f / (1.0f + expf(-delta[0]));
  float s = 0.f;
  for (int i = tid; i < LL; i += 256) {
    float v = q[i] / (d[i] + 1e-12f);
    float p = gamma[i];
    float u = p + dlt * (v - p);
    vvec[i] = v;
    uvec[i] = u;
    s += u;
  }
  float mu = blk_red_sum(s) * (1.0f / LL);
  float s2 = 0.f;
  for (int i = tid; i < LL; i += 256) { float dd = uvec[i] - mu; s2 += dd * dd; }
  float var = blk_red_sum(s2) * (1.0f / LL);
  float inv = rsqrtf(var + 1e-5f);
  for (int i = tid; i < LL; i += 256) up[i] = (uvec[i] - mu) * inv * lnw[i] + lnb[i];
}

// ---------------- gate row + attention row + final combine ----------------
__global__ __launch_bounds__(256) void k_gateattn(const float* __restrict__ ws,
                                                  const float* __restrict__ Wg,
                                                  const float* __restrict__ gb,
                                                  const float* __restrict__ inw,
                                                  const float* __restrict__ inb,
                                                  const float* __restrict__ outw,
                                                  const float* __restrict__ outb,
                                                  const float* __restrict__ gamma,
                                                  const float* __restrict__ lmbda,
                                                  float* __restrict__ out) {
  const float* uvec = ws + OFF_U;
  const float* up = ws + OFF_UP;
  const float* vvec = ws + OFF_V;
  int i = blockIdx.x, tid = threadIdx.x;
  const float4* wr = (const float4*)(Wg + (size_t)i * LL);
  const float4* u4 = (const float4*)uvec;
  float s = 0.f;
  for (int j = tid; j < LL / 4; j += 256) {
    float4 w = wr[j], x = u4[j];
    s += w.x * x.x + w.y * x.y + w.z * x.z + w.w * x.w;
  }
  float tot = blk_red_sum(s);
  float g = 1.0f / (1.0f + expf(-(tot + gb[i])));
  float qv = up[i] * inw[0] + inb[0];
  float w1 = inw[1], b1 = inb[1], w2 = inw[2], b2 = inb[2];
  const float4* up4 = (const float4*)up;
  float mx = -3.4e38f;
  for (int j = tid; j < LL / 4; j += 256) {
    float4 u = up4[j];
    mx = fmaxf(mx, fmaxf(fmaxf(qv * (u.x * w1 + b1), qv * (u.y * w1 + b1)),
                         fmaxf(qv * (u.z * w1 + b1), qv * (u.w * w1 + b1))));
  }
  mx = blk_red_max(mx);
  float den = 0.f, num = 0.f;
  for (int j = tid; j < LL / 4; j += 256) {
    float4 u = up4[j];
    float e0 = expf(qv * (u.x * w1 + b1) - mx);
    float e1 = expf(qv * (u.y * w1 + b1) - mx);
    float e2 = expf(qv * (u.z * w1 + b1) - mx);
    float e3 = expf(qv * (u.w * w1 + b1) - mx);
    den += e0 + e1 + e2 + e3;
    num += e0 * (u.x * w2 + b2) + e1 * (u.y * w2 + b2) + e2 * (u.z * w2 + b2) + e3 * (u.w * w2 + b2);
  }
  den = blk_red_sum(den);
  num = blk_red_sum(num);
  if (tid == 0) {
    float attn = (num / den) * outw[0] + outb[0];
    float r = g * vvec[i] + (1.0f - g) * gamma[i] + attn - lmbda[0];
    out[i] = fmaxf(r, 0.0f);
  }
}

extern "C" void kernel_launch(void* const* d_in, const int* in_sizes, int n_in,
                              void* d_out, int out_size, void* d_ws, size_t ws_size,
                              hipStream_t stream) {
  const float* gamma = (const float*)d_in[0];
  const float* Are   = (const float*)d_in[1];
  const float* Aim   = (const float*)d_in[2];
  const float* Xre   = (const float*)d_in[3];
  const float* Xim   = (const float*)d_in[4];
  const float* lnw   = (const float*)d_in[5];
  const float* lnb   = (const float*)d_in[6];
  const float* inw   = (const float*)d_in[7];
  const float* inb   = (const float*)d_in[8];
  const float* outw  = (const float*)d_in[9];
  const float* outb  = (const float*)d_in[10];
  const float* gateW = (const float*)d_in[11];
  const float* gateb = (const float*)d_in[12];
  const float* delta = (const float*)d_in[13];
  const float* lmbda = (const float*)d_in[14];
  float* out = (float*)d_out;
  float* ws = (float*)d_ws;

  float2* XA = (float2*)(ws + OFF_XA);
  float2* XB = (float2*)(ws + OFF_XB);
  float2* EA = (float2*)(ws + OFF_EA);
  float2* EB = (float2*)(ws + OFF_EB);
  ushort_t* Rinvp = (ushort_t*)(ws + OFF_RINVP);

  int prep_blocks = ZERO_FL / 256 + (MM * LL) / 256 + (MM * TT) / 256;
  k_prep<<<prep_blocks, 256, 0, stream>>>(ws, Are, Aim, Xre, Xim, gamma);
  k_gram_both<<<480, 256, 0, stream>>>(ws);
  k_mid<<<1280, 256, 0, stream>>>(ws, Are, Aim);

  // Newton-Schulz (5 iters): E = I - XR; X' = (I+E)X, E' = E^2. Residual E0^32 ~ 3e-8.
  k_newt_init<<<256, 256, 0, stream>>>(ws);                       // X1->XA, E0->EA
  k_newt_step<<<256, 256, 0, stream>>>(XA, EA, XB, EB, 0);        // E1->EB
  k_newt_step<<<512, 256, 0, stream>>>(XA, EB, XB, EA, 256);      // X2->XB, E2->EA
  k_newt_step<<<512, 256, 0, stream>>>(XB, EA, XA, EB, 256);      // X3->XA, E3->EB
  k_newt_step<<<512, 256, 0, stream>>>(XA, EB, XB, EA, 256);      // X4->XB, E4->EA
  k_newt_fin<<<256, 256, 0, stream>>>(XB, EA, Rinvp);             // X5 -> planes

  k_wide_mfma<<<dim3(64, 4), 256, 0, stream>>>(Rinvp, (ushort_t*)(ws + OFF_ATP),
                                               Are, Aim, (ushort_t*)(ws + OFF_WTP),
                                               ws + OFF_D, 0);
  k_wide_mfma<<<dim3(64, 4), 256, 0, stream>>>((ushort_t*)(ws + OFF_GP),
                                               (ushort_t*)(ws + OFF_WTP),
                                               nullptr, nullptr, nullptr, ws + OFF_Q, 1);
  k_uvln<<<1, 256, 0, stream>>>(ws, gamma, delta, lnw, lnb);
  k_gateattn<<<LL, 256, 0, stream>>>(ws, gateW, gateb, inw, inb, outw, outb, gamma, lmbda, out);
}

// Round 8
// 308.244 us; speedup vs baseline: 3.9079x; 1.0445x over previous
//
#include <hip/hip_runtime.h>
#include <hip/hip_bf16.h>
#include <math.h>

#define MM 256
#define LL 4096
#define TT 2048

typedef __attribute__((ext_vector_type(8))) short bf16x8;
typedef __attribute__((ext_vector_type(4))) float f32x4;
typedef __attribute__((ext_vector_type(4))) unsigned short us4;
typedef unsigned short ushort_t;

// workspace float offsets
#define OFF_G      131072
#define OFF_Q      262144
#define OFF_D      266240
#define OFF_V      270336
#define OFF_U      274432
#define OFF_UP     278528
#define ZERO_FL    290816   // zero range [0, ZERO_FL)
#define OFF_RINVP  290816
#define OFF_GP     421888
#define OFF_APL    552960
#define OFF_XPL    2650112
#define OFF_ATP    3698688
#define OFF_WTP    5795840
#define OFF_XA     9990144
#define OFF_XB     10121216
#define OFF_EA     10252288
#define OFF_EB     10383360

#define MFMA3(ACC, AH, AL, BH, BL)                                              \
  ACC = __builtin_amdgcn_mfma_f32_16x16x32_bf16(AH, BH, ACC, 0, 0, 0);          \
  ACC = __builtin_amdgcn_mfma_f32_16x16x32_bf16(AH, BL, ACC, 0, 0, 0);          \
  ACC = __builtin_amdgcn_mfma_f32_16x16x32_bf16(AL, BH, ACC, 0, 0, 0);

__device__ __forceinline__ void split_bf16(float x, ushort_t& h, ushort_t& l) {
  __hip_bfloat16 bh = __float2bfloat16(x);
  h = *(ushort_t*)&bh;
  __hip_bfloat16 bl = __float2bfloat16(x - __bfloat162float(bh));
  l = *(ushort_t*)&bl;
}
__device__ __forceinline__ float bfu2f(ushort_t u) {
  unsigned v = ((unsigned)u) << 16;
  float f;
  __builtin_memcpy(&f, &v, 4);
  return f;
}

// ---------------- reductions ----------------
__device__ __forceinline__ float wave_red_sum(float v) {
#pragma unroll
  for (int o = 32; o > 0; o >>= 1) v += __shfl_down(v, o);
  return v;
}
__device__ __forceinline__ float wave_red_max(float v) {
#pragma unroll
  for (int o = 32; o > 0; o >>= 1) v = fmaxf(v, __shfl_down(v, o));
  return v;
}
__device__ float blk_red_sum(float v) {
  __shared__ float sh[4];
  int lane = threadIdx.x & 63, wv = threadIdx.x >> 6;
  v = wave_red_sum(v);
  __syncthreads();
  if (lane == 0) sh[wv] = v;
  __syncthreads();
  return sh[0] + sh[1] + sh[2] + sh[3];
}
__device__ float blk_red_max(float v) {
  __shared__ float shm[4];
  int lane = threadIdx.x & 63, wv = threadIdx.x >> 6;
  v = wave_red_max(v);
  __syncthreads();
  if (lane == 0) shm[wv] = v;
  __syncthreads();
  return fmaxf(fmaxf(shm[0], shm[1]), fmaxf(shm[2], shm[3]));
}

// mirrored R element (lower tiles valid; upper = conj of mirror)
__device__ __forceinline__ float2 r_mirror(const float2* __restrict__ R, int i, int j) {
  if ((i >> 6) >= (j >> 6)) return R[i * 256 + j];
  float2 r = R[j * 256 + i];
  r.y = -r.y;
  return r;
}

// ---------------- prep: zero + A/X -> split-bf16 planes (vectorized) + A^T planes ----------
// blocks: [0,1136) zero; [1136,2160) A conv (f4); [2160,2672) X conv (f4); [2672,3696) transpA
__global__ __launch_bounds__(256) void k_prep(float* __restrict__ ws,
                                              const float* __restrict__ Are,
                                              const float* __restrict__ Aim,
                                              const float* __restrict__ Xre,
                                              const float* __restrict__ Xim,
                                              const float* __restrict__ gamma) {
  __shared__ float tr[32][33], ti[32][33];
  int bid = blockIdx.x, tid = threadIdx.x;
  if (bid < 1136) {                                // zero R,G,q,d,v,u,up
    int idx = bid * 256 + tid;
    float v = 0.0f;
    if (idx < 131072 && (idx % 514) == 0) v = 0.01f;  // ridge on R diag (.x)
    ws[idx] = v;
  } else if (bid < 2160) {                         // A -> planes, sqrt(gamma) folded
    int i4 = (bid - 1136) * 256 + tid;             // float4 index, 262144 total
    ushort_t* dst = (ushort_t*)(ws + OFF_APL);
    float4 re = ((const float4*)Are)[i4];
    float4 im = ((const float4*)Aim)[i4];
    float4 ga = ((const float4*)gamma)[i4 & (LL / 4 - 1)];
    float sr[4] = {re.x * sqrtf(ga.x), re.y * sqrtf(ga.y), re.z * sqrtf(ga.z), re.w * sqrtf(ga.w)};
    float si[4] = {im.x * sqrtf(ga.x), im.y * sqrtf(ga.y), im.z * sqrtf(ga.z), im.w * sqrtf(ga.w)};
    us4 hr, lr, hi, li;
#pragma unroll
    for (int e = 0; e < 4; ++e) {
      ushort_t h, l;
      split_bf16(sr[e], h, l); hr[e] = h; lr[e] = l;
      split_bf16(si[e], h, l); hi[e] = h; li[e] = l;
    }
    size_t o = (size_t)i4 * 4;
    *(us4*)(dst + o) = hr;
    *(us4*)(dst + (size_t)MM * LL + o) = lr;
    *(us4*)(dst + 2 * (size_t)MM * LL + o) = hi;
    *(us4*)(dst + 3 * (size_t)MM * LL + o) = li;
  } else if (bid < 2672) {                         // X -> planes
    int i4 = (bid - 2160) * 256 + tid;             // 131072 total
    ushort_t* dst = (ushort_t*)(ws + OFF_XPL);
    float4 re = ((const float4*)Xre)[i4];
    float4 im = ((const float4*)Xim)[i4];
    float fr[4] = {re.x, re.y, re.z, re.w};
    float fi[4] = {im.x, im.y, im.z, im.w};
    us4 hr, lr, hi, li;
#pragma unroll
    for (int e = 0; e < 4; ++e) {
      ushort_t h, l;
      split_bf16(fr[e], h, l); hr[e] = h; lr[e] = l;
      split_bf16(fi[e], h, l); hi[e] = h; li[e] = l;
    }
    size_t o = (size_t)i4 * 4;
    *(us4*)(dst + o) = hr;
    *(us4*)(dst + (size_t)MM * TT + o) = lr;
    *(us4*)(dst + 2 * (size_t)MM * TT + o) = hi;
    *(us4*)(dst + 3 * (size_t)MM * TT + o) = li;
  } else {                                         // transpA: [256][4096] -> planes [4096][256]
    int b2 = bid - 2672;
    ushort_t* dst = (ushort_t*)(ws + OFF_ATP);
    int c0 = (b2 & 127) * 32, r0 = (b2 >> 7) * 32;
    int tx = tid & 31, tg = tid >> 5;
#pragma unroll
    for (int i = 0; i < 4; ++i) {
      int r = tg + 8 * i;
      tr[r][tx] = Are[(size_t)(r0 + r) * LL + c0 + tx];
      ti[r][tx] = Aim[(size_t)(r0 + r) * LL + c0 + tx];
    }
    __syncthreads();
#pragma unroll
    for (int i = 0; i < 4; ++i) {
      int rr = tg + 8 * i;
      size_t o = (size_t)(c0 + rr) * 256 + r0 + tx;
      ushort_t h, l;
      split_bf16(tr[tx][rr], h, l);
      dst[o] = h;
      dst[o + 1048576] = l;
      split_bf16(ti[tx][rr], h, l);
      dst[o + 2097152] = h;
      dst[o + 3145728] = l;
    }
  }
}

// ---------------- gram v3: LDS-staged, Hermitian lower tiles only ----------------
__global__ __launch_bounds__(256, 4) void k_gram_both(float* __restrict__ ws) {
  __shared__ __align__(16) ushort_t sA[4][64][40];
  __shared__ __align__(16) ushort_t sB[4][64][40];
  const int ti_lu[10] = {0, 1, 1, 2, 2, 2, 3, 3, 3, 3};
  const int tj_lu[10] = {0, 0, 1, 0, 1, 2, 0, 1, 2, 3};
  int bid = blockIdx.x;
  const ushort_t* pl;
  float* C;
  int K, tile, ksplit;
  size_t PS;
  if (bid < 320) {
    pl = (const ushort_t*)(ws + OFF_APL);
    C = ws;
    K = LL;
    PS = (size_t)MM * LL;
    tile = bid % 10;
    ksplit = bid / 10;
  } else {
    int b2 = bid - 320;
    pl = (const ushort_t*)(ws + OFF_XPL);
    C = ws + OFF_G;
    K = TT;
    PS = (size_t)MM * TT;
    tile = b2 % 10;
    ksplit = b2 / 10;
  }
  int kbeg = ksplit * 128;
  int i0 = ti_lu[tile] * 64, j0 = tj_lu[tile] * 64;
  bool diag = (i0 == j0);
  int tid = threadIdx.x;
  int lane = tid & 63, wv = tid >> 6;
  int srow = tid >> 2, sslot = tid & 3;
  int arow = wv * 16 + (lane & 15);
  int kq = (lane >> 4) * 8;
  f32x4 z = {0.f, 0.f, 0.f, 0.f};
  f32x4 Zrr[4], Zri[4], Zir[4], Zii[4];
#pragma unroll
  for (int s = 0; s < 4; ++s) { Zrr[s] = z; Zri[s] = z; Zir[s] = z; Zii[s] = z; }

  for (int chunk = 0; chunk < 4; ++chunk) {
    int k0 = kbeg + chunk * 32;
    __syncthreads();
#pragma unroll
    for (int p = 0; p < 4; ++p) {
      *(bf16x8*)&sA[p][srow][sslot * 8] =
          *(const bf16x8*)(pl + p * PS + (size_t)(i0 + srow) * K + k0 + sslot * 8);
      if (!diag)
        *(bf16x8*)&sB[p][srow][sslot * 8] =
            *(const bf16x8*)(pl + p * PS + (size_t)(j0 + srow) * K + k0 + sslot * 8);
    }
    __syncthreads();
    bf16x8 arh = *(const bf16x8*)&sA[0][arow][kq];
    bf16x8 arl = *(const bf16x8*)&sA[1][arow][kq];
    bf16x8 aih = *(const bf16x8*)&sA[2][arow][kq];
    bf16x8 ail = *(const bf16x8*)&sA[3][arow][kq];
    ushort_t(*bs)[64][40] = diag ? sA : sB;
#pragma unroll
    for (int s = 0; s < 4; ++s) {
      int brow = s * 16 + (lane & 15);
      bf16x8 brh = *(const bf16x8*)&bs[0][brow][kq];
      bf16x8 brl = *(const bf16x8*)&bs[1][brow][kq];
      bf16x8 bih = *(const bf16x8*)&bs[2][brow][kq];
      bf16x8 bil = *(const bf16x8*)&bs[3][brow][kq];
      MFMA3(Zrr[s], arh, arl, brh, brl);
      MFMA3(Zri[s], arh, arl, bih, bil);
      MFMA3(Zir[s], aih, ail, brh, brl);
      MFMA3(Zii[s], aih, ail, bih, bil);
    }
  }
  int rbase = i0 + wv * 16 + (lane >> 4) * 4;
#pragma unroll
  for (int s = 0; s < 4; ++s) {
    int col = j0 + s * 16 + (lane & 15);
#pragma unroll
    for (int r = 0; r < 4; ++r) {
      float re = Zrr[s][r] + Zii[s][r];   // a * conj(b)
      float im = Zir[s][r] - Zri[s][r];
      float* p = C + ((size_t)(rbase + r) * 256 + col) * 2;
      atomicAdd(p, re);
      atomicAdd(p + 1, im);
    }
  }
}

// ---------------- n1: E1 = E0^2 (E0 on-the-fly from R) + X1 elementwise + G -> Gp ------
// blocks [0,256): E1 matmul tiles; [256,512): X1; [512,768): Gp conversion
__global__ __launch_bounds__(256) void k_n1(float* __restrict__ ws) {
  __shared__ float2 As[16][17], Bs[16][17];
  const float2* R = (const float2*)ws;
  int bid = blockIdx.x, tid = threadIdx.x;
  if (bid < 256) {  // E1 = E0 @ E0 -> EA
    float2* E1 = (float2*)(ws + OFF_EA);
    int i0 = (bid >> 4) * 16, j0 = (bid & 15) * 16;
    int tx = tid & 15, ty = tid >> 4;
    int rowA = i0 + ty;
    float DiA = R[rowA * 257].x;
    float accx = 0.f, accy = 0.f;
    for (int k0 = 0; k0 < 256; k0 += 16) {
      __syncthreads();
      {  // As[ty][tx] = E0(rowA, k0+tx)
        int c = k0 + tx;
        float2 r = r_mirror(R, rowA, c);
        float dl = (rowA == c) ? 1.0f : 0.0f;
        As[ty][tx] = make_float2(dl - r.x / DiA, -r.y / DiA);
      }
      {  // Bs[ty][tx] = E0(k0+ty, j0+tx)
        int rB = k0 + ty, c = j0 + tx;
        float DiB = R[rB * 257].x;
        float2 r = r_mirror(R, rB, c);
        float dl = (rB == c) ? 1.0f : 0.0f;
        Bs[ty][tx] = make_float2(dl - r.x / DiB, -r.y / DiB);
      }
      __syncthreads();
#pragma unroll
      for (int kk = 0; kk < 16; ++kk) {
        float2 a = As[ty][kk], bb = Bs[kk][tx];
        accx += a.x * bb.x - a.y * bb.y;
        accy += a.x * bb.y + a.y * bb.x;
      }
    }
    E1[rowA * 256 + j0 + tx] = make_float2(accx, accy);
  } else if (bid < 512) {  // X1 = (I + E0) D^-1  -> XA
    float2* X1 = (float2*)(ws + OFF_XA);
    int idx = (bid - 256) * 256 + tid;
    int i = idx >> 8, j = idx & 255;
    float Dii = R[i * 257].x;
    float Djj = R[j * 257].x;
    float2 r = r_mirror(R, i, j);
    float dl = (i == j) ? 1.0f : 0.0f;
    float ex = dl - r.x / Dii;
    float ey = -r.y / Dii;
    X1[idx] = make_float2((dl + ex) / Djj, ey / Djj);
  } else {  // G -> Gp (Hermitian mirror)
    const float2* src = (const float2*)(ws + OFF_G);
    ushort_t* dst = (ushort_t*)(ws + OFF_GP);
    int idx = (bid - 512) * 256 + tid;
    int i = idx >> 8, j = idx & 255;
    float2 v = r_mirror(src, i, j);
    ushort_t h, l;
    split_bf16(v.x, h, l);
    dst[idx] = h;
    dst[idx + 65536] = l;
    split_bf16(v.y, h, l);
    dst[idx + 131072] = h;
    dst[idx + 196608] = l;
  }
}

// ---------------- coupled Newton step ----------------
// blocks [0,xblocks): Xout = Xin + Ein@Xin ; blocks [xblocks,...): Eout = Ein@Ein
__global__ __launch_bounds__(256) void k_newt_step(const float2* __restrict__ Xin,
                                                   const float2* __restrict__ Ein,
                                                   float2* __restrict__ Xout,
                                                   float2* __restrict__ Eout, int xblocks) {
  __shared__ float2 As[16][17], Bs[16][17];
  int bid = blockIdx.x;
  bool isX = bid < xblocks;
  int b = isX ? bid : bid - xblocks;
  const float2* Bm = isX ? Xin : Ein;
  int i0 = (b >> 4) * 16, j0 = (b & 15) * 16;
  int tx = threadIdx.x & 15, ty = threadIdx.x >> 4;
  float accx = 0.f, accy = 0.f;
  for (int k0 = 0; k0 < 256; k0 += 16) {
    __syncthreads();
    As[ty][tx] = Ein[(i0 + ty) * 256 + k0 + tx];
    Bs[ty][tx] = Bm[(k0 + ty) * 256 + j0 + tx];
    __syncthreads();
#pragma unroll
    for (int kk = 0; kk < 16; ++kk) {
      float2 a = As[ty][kk], bb = Bs[kk][tx];
      accx += a.x * bb.x - a.y * bb.y;
      accy += a.x * bb.y + a.y * bb.x;
    }
  }
  int idx = (i0 + ty) * 256 + j0 + tx;
  if (isX) {
    float2 x = Xin[idx];
    Xout[idx] = make_float2(x.x + accx, x.y + accy);
  } else {
    Eout[idx] = make_float2(accx, accy);
  }
}

// ---------------- Newton final: X' = Xin + Ein@Xin -> split-bf16 planes ----------------
__global__ __launch_bounds__(256) void k_newt_fin(const float2* __restrict__ Xin,
                                                  const float2* __restrict__ Ein,
                                                  ushort_t* __restrict__ dst) {
  __shared__ float2 As[16][17], Bs[16][17];
  int b = blockIdx.x;
  int i0 = (b >> 4) * 16, j0 = (b & 15) * 16;
  int tx = threadIdx.x & 15, ty = threadIdx.x >> 4;
  float accx = 0.f, accy = 0.f;
  for (int k0 = 0; k0 < 256; k0 += 16) {
    __syncthreads();
    As[ty][tx] = Ein[(i0 + ty) * 256 + k0 + tx];
    Bs[ty][tx] = Xin[(k0 + ty) * 256 + j0 + tx];
    __syncthreads();
#pragma unroll
    for (int kk = 0; kk < 16; ++kk) {
      float2 a = As[ty][kk], bb = Bs[kk][tx];
      accx += a.x * bb.x - a.y * bb.y;
      accy += a.x * bb.y + a.y * bb.x;
    }
  }
  int idx = (i0 + ty) * 256 + j0 + tx;
  float2 x = Xin[idx];
  float vx = x.x + accx, vy = x.y + accy;
  ushort_t h, l;
  split_bf16(vx, h, l);
  dst[idx] = h;
  dst[idx + 65536] = l;
  split_bf16(vy, h, l);
  dst[idx + 131072] = h;
  dst[idx + 196608] = l;
}

// ---------------- wide MFMA (B LDS-staged): (256x256) @ (256x4096) ----------------
// mode 0: write W^T split-bf16 planes + d[l] atomics; mode 1: q[l] atomics
__global__ __launch_bounds__(256) void k_wide_mfma(const ushort_t* __restrict__ Ap,
                                                   const ushort_t* __restrict__ Bp,
                                                   const float* __restrict__ AuxRe,
                                                   const float* __restrict__ AuxIm,
                                                   ushort_t* __restrict__ WTout,
                                                   float* __restrict__ dq, int mode) {
  __shared__ __align__(16) ushort_t sB[4][64][40];
  const ushort_t* arh_p = Ap;
  const ushort_t* arl_p = Ap + 65536;
  const ushort_t* aih_p = Ap + 131072;
  const ushort_t* ail_p = Ap + 196608;
  const ushort_t* brh_p = Bp;
  const ushort_t* brl_p = Bp + 1048576;
  const ushort_t* bih_p = Bp + 2097152;
  const ushort_t* bil_p = Bp + 3145728;
  int j0 = blockIdx.x * 64;  // l
  int i0 = blockIdx.y * 64;  // m
  int tid = threadIdx.x;
  int lane = tid & 63, wv = tid >> 6;
  int srow = tid >> 2, sslot = tid & 3;
  int m = i0 + wv * 16 + (lane & 15);
  int kq = (lane >> 4) * 8;
  f32x4 z = {0.f, 0.f, 0.f, 0.f};
  f32x4 Zrr[4], Zri[4], Zir[4], Zii[4];
#pragma unroll
  for (int s = 0; s < 4; ++s) { Zrr[s] = z; Zri[s] = z; Zir[s] = z; Zii[s] = z; }
  for (int k0 = 0; k0 < 256; k0 += 32) {
    __syncthreads();
    {
      size_t bo = (size_t)(j0 + srow) * 256 + k0 + sslot * 8;
      *(bf16x8*)&sB[0][srow][sslot * 8] = *(const bf16x8*)(brh_p + bo);
      *(bf16x8*)&sB[1][srow][sslot * 8] = *(const bf16x8*)(brl_p + bo);
      *(bf16x8*)&sB[2][srow][sslot * 8] = *(const bf16x8*)(bih_p + bo);
      *(bf16x8*)&sB[3][srow][sslot * 8] = *(const bf16x8*)(bil_p + bo);
    }
    __syncthreads();
    size_t ao = (size_t)m * 256 + k0 + kq;
    bf16x8 arh = *(const bf16x8*)(arh_p + ao);
    bf16x8 arl = *(const bf16x8*)(arl_p + ao);
    bf16x8 aih = *(const bf16x8*)(aih_p + ao);
    bf16x8 ail = *(const bf16x8*)(ail_p + ao);
#pragma unroll
    for (int s = 0; s < 4; ++s) {
      int brow = s * 16 + (lane & 15);
      bf16x8 brh = *(const bf16x8*)&sB[0][brow][kq];
      bf16x8 brl = *(const bf16x8*)&sB[1][brow][kq];
      bf16x8 bih = *(const bf16x8*)&sB[2][brow][kq];
      bf16x8 bil = *(const bf16x8*)&sB[3][brow][kq];
      MFMA3(Zrr[s], arh, arl, brh, brl);
      MFMA3(Zri[s], arh, arl, bih, bil);
      MFMA3(Zir[s], aih, ail, brh, brl);
      MFMA3(Zii[s], aih, ail, bih, bil);
    }
  }
  int rbase = i0 + wv * 16 + (lane >> 4) * 4;
#pragma unroll
  for (int s = 0; s < 4; ++s) {
    int col = j0 + s * 16 + (lane & 15);
    size_t wo = (size_t)col * 256 + rbase;
    float part = 0.f;
    if (mode == 0) {
      us4 hr, lr, hi, li;
#pragma unroll
      for (int r = 0; r < 4; ++r) {
        float re = Zrr[s][r] - Zii[s][r];   // a * b
        float im = Zri[s][r] + Zir[s][r];
        ushort_t h, l;
        split_bf16(re, h, l);
        hr[r] = h; lr[r] = l;
        split_bf16(im, h, l);
        hi[r] = h; li[r] = l;
        size_t o = (size_t)(rbase + r) * LL + col;
        part += re * AuxRe[o] - im * AuxIm[o];
      }
      *(us4*)(WTout + wo) = hr;
      *(us4*)(WTout + 1048576 + wo) = lr;
      *(us4*)(WTout + 2097152 + wo) = hi;
      *(us4*)(WTout + 3145728 + wo) = li;
    } else {
      us4 wh = *(const us4*)(brh_p + wo);
      us4 wl = *(const us4*)(brl_p + wo);
      us4 wih = *(const us4*)(bih_p + wo);
      us4 wil = *(const us4*)(bil_p + wo);
#pragma unroll
      for (int r = 0; r < 4; ++r) {
        float re = Zrr[s][r] - Zii[s][r];
        float im = Zri[s][r] + Zir[s][r];
        float wx = bfu2f(wh[r]) + bfu2f(wl[r]);
        float wy = bfu2f(wih[r]) + bfu2f(wil[r]);
        part += wx * re + wy * im;
      }
    }
    part += __shfl_down(part, 32);
    part += __shfl_down(part, 16);
    if ((lane >> 4) == 0) atomicAdd(dq + col, part);
  }
}

// ---------------- v,u + LayerNorm (single block) ----------------
__global__ __launch_bounds__(256) void k_uvln(float* __restrict__ ws,
                                              const float* __restrict__ gamma,
                                              const float* __restrict__ delta,
                                              const float* __restrict__ lnw,
                                              const float* __restrict__ lnb) {
  const float* q = ws + OFF_Q;
  const float* d = ws + OFF_D;
  float* vvec = ws + OFF_V;
  float* uvec = ws + OFF_U;
  float* up = ws + OFF_UP;
  int tid = threadIdx.x;
  float dlt = 1.0f / (1.0f + expf(-delta[0]));
  float s = 0.f;
  for (int i = tid; i < LL; i += 256) {
    float v = q[i] / (d[i] + 1e-12f);
    float p = gamma[i];
    float u = p + dlt * (v - p);
    vvec[i] = v;
    uvec[i] = u;
    s += u;
  }
  float mu = blk_red_sum(s) * (1.0f / LL);
  float s2 = 0.f;
  for (int i = tid; i < LL; i += 256) { float dd = uvec[i] - mu; s2 += dd * dd; }
  float var = blk_red_sum(s2) * (1.0f / LL);
  float inv = rsqrtf(var + 1e-5f);
  for (int i = tid; i < LL; i += 256) up[i] = (uvec[i] - mu) * inv * lnw[i] + lnb[i];
}

// ---------------- gate row + attention row + final combine ----------------
__global__ __launch_bounds__(256) void k_gateattn(const float* __restrict__ ws,
                                                  const float* __restrict__ Wg,
                                                  const float* __restrict__ gb,
                                                  const float* __restrict__ inw,
                                                  const float* __restrict__ inb,
                                                  const float* __restrict__ outw,
                                                  const float* __restrict__ outb,
                                                  const float* __restrict__ gamma,
                                                  const float* __restrict__ lmbda,
                                                  float* __restrict__ out) {
  const float* uvec = ws + OFF_U;
  const float* up = ws + OFF_UP;
  const float* vvec = ws + OFF_V;
  int i = blockIdx.x, tid = threadIdx.x;
  const float4* wr = (const float4*)(Wg + (size_t)i * LL);
  const float4* u4 = (const float4*)uvec;
  float s = 0.f;
  for (int j = tid; j < LL / 4; j += 256) {
    float4 w = wr[j], x = u4[j];
    s += w.x * x.x + w.y * x.y + w.z * x.z + w.w * x.w;
  }
  float tot = blk_red_sum(s);
  float g = 1.0f / (1.0f + expf(-(tot + gb[i])));
  float qv = up[i] * inw[0] + inb[0];
  float w1 = inw[1], b1 = inb[1], w2 = inw[2], b2 = inb[2];
  const float4* up4 = (const float4*)up;
  float mx = -3.4e38f;
  for (int j = tid; j < LL / 4; j += 256) {
    float4 u = up4[j];
    mx = fmaxf(mx, fmaxf(fmaxf(qv * (u.x * w1 + b1), qv * (u.y * w1 + b1)),
                         fmaxf(qv * (u.z * w1 + b1), qv * (u.w * w1 + b1))));
  }
  mx = blk_red_max(mx);
  float den = 0.f, num = 0.f;
  for (int j = tid; j < LL / 4; j += 256) {
    float4 u = up4[j];
    float e0 = expf(qv * (u.x * w1 + b1) - mx);
    float e1 = expf(qv * (u.y * w1 + b1) - mx);
    float e2 = expf(qv * (u.z * w1 + b1) - mx);
    float e3 = expf(qv * (u.w * w1 + b1) - mx);
    den += e0 + e1 + e2 + e3;
    num += e0 * (u.x * w2 + b2) + e1 * (u.y * w2 + b2) + e2 * (u.z * w2 + b2) + e3 * (u.w * w2 + b2);
  }
  den = blk_red_sum(den);
  num = blk_red_sum(num);
  if (tid == 0) {
    float attn = (num / den) * outw[0] + outb[0];
    float r = g * vvec[i] + (1.0f - g) * gamma[i] + attn - lmbda[0];
    out[i] = fmaxf(r, 0.0f);
  }
}

extern "C" void kernel_launch(void* const* d_in, const int* in_sizes, int n_in,
                              void* d_out, int out_size, void* d_ws, size_t ws_size,
                              hipStream_t stream) {
  const float* gamma = (const float*)d_in[0];
  const float* Are   = (const float*)d_in[1];
  const float* Aim   = (const float*)d_in[2];
  const float* Xre   = (const float*)d_in[3];
  const float* Xim   = (const float*)d_in[4];
  const float* lnw   = (const float*)d_in[5];
  const float* lnb   = (const float*)d_in[6];
  const float* inw   = (const float*)d_in[7];
  const float* inb   = (const float*)d_in[8];
  const float* outw  = (const float*)d_in[9];
  const float* outb  = (const float*)d_in[10];
  const float* gateW = (const float*)d_in[11];
  const float* gateb = (const float*)d_in[12];
  const float* delta = (const float*)d_in[13];
  const float* lmbda = (const float*)d_in[14];
  float* out = (float*)d_out;
  float* ws = (float*)d_ws;

  float2* XA = (float2*)(ws + OFF_XA);
  float2* XB = (float2*)(ws + OFF_XB);
  float2* EA = (float2*)(ws + OFF_EA);
  float2* EB = (float2*)(ws + OFF_EB);
  ushort_t* Rinvp = (ushort_t*)(ws + OFF_RINVP);

  k_prep<<<3696, 256, 0, stream>>>(ws, Are, Aim, Xre, Xim, gamma);
  k_gram_both<<<480, 256, 0, stream>>>(ws);
  // n1: X1 (res E0^2) + E1 = E0^2 + Gp conversion
  k_n1<<<768, 256, 0, stream>>>(ws);
  // quadratic chain to residual E0^32 (same numerics as proven round-7):
  k_newt_step<<<512, 256, 0, stream>>>(XA, EA, XB, EB, 256);      // X2 (E0^4),  E2=E0^4
  k_newt_step<<<512, 256, 0, stream>>>(XB, EB, XA, EA, 256);      // X3 (E0^8),  E3=E0^8
  k_newt_step<<<512, 256, 0, stream>>>(XA, EA, XB, EB, 256);      // X4 (E0^16), E4=E0^16
  k_newt_fin<<<256, 256, 0, stream>>>(XB, EB, Rinvp);             // X5 (E0^32) -> planes

  k_wide_mfma<<<dim3(64, 4), 256, 0, stream>>>(Rinvp, (ushort_t*)(ws + OFF_ATP),
                                               Are, Aim, (ushort_t*)(ws + OFF_WTP),
                                               ws + OFF_D, 0);
  k_wide_mfma<<<dim3(64, 4), 256, 0, stream>>>((ushort_t*)(ws + OFF_GP),
                                               (ushort_t*)(ws + OFF_WTP),
                                               nullptr, nullptr, nullptr, ws + OFF_Q, 1);
  k_uvln<<<1, 256, 0, stream>>>(ws, gamma, delta, lnw, lnb);
  k_gateattn<<<LL, 256, 0, stream>>>(ws, gateW, gateb, inw, inb, outw, outb, gamma, lmbda, out);
}